// Round 1
// baseline (1121.443 us; speedup 1.0000x reference)
//
#include <hip/hip_runtime.h>
#include <math.h>

#define N_NODES 40000
#define N_EDGES 640000
#define FIN 64
#define HID 128
#define OUTDIM 64
#define HEADS 4
#define NGROUPS 64
#define NCOLS 512   // HEADS*HID

__device__ __forceinline__ float lrelu(float x) { return x > 0.f ? x : 0.2f * x; }

// ---------------- CSR build ----------------
__global__ void deg_init_kernel(int* deg) {
    int i = blockIdx.x * blockDim.x + threadIdx.x;
    if (i < N_NODES) deg[i] = 1;   // self loop
}

__global__ void deg_count_kernel(const int* __restrict__ ei, int* deg) {
    int e = blockIdx.x * blockDim.x + threadIdx.x;
    if (e < N_EDGES) atomicAdd(&deg[ei[N_EDGES + e]], 1);
}

__global__ void scan_kernel(const int* __restrict__ deg, int* offsets, int* pos) {
    __shared__ int buf[1024];
    __shared__ int carry_s;
    int t = threadIdx.x;
    if (t == 0) carry_s = 0;
    __syncthreads();
    for (int base = 0; base < N_NODES; base += 1024) {
        int v = (base + t < N_NODES) ? deg[base + t] : 0;
        buf[t] = v;
        __syncthreads();
        for (int off = 1; off < 1024; off <<= 1) {
            int y = (t >= off) ? buf[t - off] : 0;
            __syncthreads();
            buf[t] += y;
            __syncthreads();
        }
        int carry = carry_s;
        if (base + t < N_NODES) {
            int excl = carry + buf[t] - v;
            offsets[base + t] = excl;
            pos[base + t] = excl;
        }
        __syncthreads();
        if (t == 1023) carry_s = carry + buf[1023];
        __syncthreads();
    }
    if (t == 0) offsets[N_NODES] = carry_s;
}

__global__ void scatter_kernel(const int* __restrict__ ei, int* pos, int* csr_src) {
    int i = blockIdx.x * blockDim.x + threadIdx.x;
    if (i < N_EDGES) {
        int s = ei[i];
        int d = ei[N_EDGES + i];
        csr_src[atomicAdd(&pos[d], 1)] = s;
    } else if (i < N_EDGES + N_NODES) {
        int nn = i - N_EDGES;
        csr_src[atomicAdd(&pos[nn], 1)] = nn;
    }
}

// ---------------- GEMM: C[M,512] = A[M,K] @ B[K,512], fp32 ----------------
__global__ __launch_bounds__(256) void gemm_kernel(const float* __restrict__ A,
                                                   const float* __restrict__ B,
                                                   float* __restrict__ C, int K) {
    __shared__ float As[16][64];
    __shared__ float Bs[16][64];
    int bm = blockIdx.x * 64;
    int bn = blockIdx.y * 64;
    int tid = threadIdx.x;
    int tx = tid & 15, ty = tid >> 4;
    float acc[4][4] = {};
    for (int k0 = 0; k0 < K; k0 += 16) {
        #pragma unroll
        for (int i = tid; i < 64 * 16; i += 256) {
            int m = i >> 4, k = i & 15;
            As[k][m] = A[(size_t)(bm + m) * K + k0 + k];
        }
        #pragma unroll
        for (int i = tid; i < 16 * 64; i += 256) {
            int k = i >> 6, n = i & 63;
            Bs[k][n] = B[(size_t)(k0 + k) * NCOLS + bn + n];
        }
        __syncthreads();
        #pragma unroll
        for (int k = 0; k < 16; ++k) {
            float a[4], bb[4];
            #pragma unroll
            for (int i = 0; i < 4; ++i) a[i] = As[k][ty * 4 + i];
            #pragma unroll
            for (int j = 0; j < 4; ++j) bb[j] = Bs[k][tx * 4 + j];
            #pragma unroll
            for (int i = 0; i < 4; ++i)
                #pragma unroll
                for (int j = 0; j < 4; ++j)
                    acc[i][j] += a[i] * bb[j];
        }
        __syncthreads();
    }
    #pragma unroll
    for (int i = 0; i < 4; ++i) {
        int row = bm + ty * 4 + i;
        #pragma unroll
        for (int j = 0; j < 4; ++j)
            C[(size_t)row * NCOLS + bn + tx * 4 + j] = acc[i][j];
    }
}

// ---------------- attention scores per node: s = <xh[n,h,:], a[h,:]> ----------------
__global__ __launch_bounds__(256) void scores_kernel(const float* __restrict__ xh,
                                                     const float* __restrict__ a_s,
                                                     const float* __restrict__ a_d,
                                                     float* __restrict__ s_src,
                                                     float* __restrict__ s_dst) {
    int node = blockIdx.x * 4 + (threadIdx.x >> 6);
    int lane = threadIdx.x & 63;
    if (node >= N_NODES) return;
    const float* row = xh + (size_t)node * NCOLS;
    float ps[HEADS], pd[HEADS];
    #pragma unroll
    for (int h = 0; h < HEADS; ++h) {
        float v0 = row[h * HID + lane], v1 = row[h * HID + 64 + lane];
        ps[h] = v0 * a_s[h * HID + lane] + v1 * a_s[h * HID + 64 + lane];
        pd[h] = v0 * a_d[h * HID + lane] + v1 * a_d[h * HID + 64 + lane];
    }
    #pragma unroll
    for (int off = 32; off > 0; off >>= 1) {
        #pragma unroll
        for (int h = 0; h < HEADS; ++h) {
            ps[h] += __shfl_down(ps[h], off);
            pd[h] += __shfl_down(pd[h], off);
        }
    }
    if (lane == 0) {
        #pragma unroll
        for (int h = 0; h < HEADS; ++h) {
            s_src[node * HEADS + h] = ps[h];
            s_dst[node * HEADS + h] = pd[h];
        }
    }
}

// ---------------- per-dst softmax + weighted aggregation + head-mean + bias + BN + ReLU --------
__global__ __launch_bounds__(128) void aggregate_kernel(const float* __restrict__ xh,
                                                        const float* __restrict__ s_src,
                                                        const float* __restrict__ s_dst,
                                                        const int* __restrict__ offsets,
                                                        const int* __restrict__ csr_src,
                                                        const float* __restrict__ bias,
                                                        const float* __restrict__ gamma,
                                                        const float* __restrict__ beta,
                                                        float* __restrict__ h_out) {
    int n = blockIdx.x;
    int t = threadIdx.x;   // channel 0..127
    int start = offsets[n], end = offsets[n + 1];
    const float4 sd = *(const float4*)(s_dst + n * 4);
    __shared__ float red[4][132];
    __shared__ float Mh[4], inv[4];
    __shared__ int csrc[128];
    __shared__ float calpha[128][4];

    // pass 1a: per-head max of leaky_relu(s_src[src]+s_dst[n])
    float mx[4] = {-1e30f, -1e30f, -1e30f, -1e30f};
    for (int j = start + t; j < end; j += 128) {
        const float4 ss = *(const float4*)(s_src + csr_src[j] * 4);
        mx[0] = fmaxf(mx[0], lrelu(ss.x + sd.x));
        mx[1] = fmaxf(mx[1], lrelu(ss.y + sd.y));
        mx[2] = fmaxf(mx[2], lrelu(ss.z + sd.z));
        mx[3] = fmaxf(mx[3], lrelu(ss.w + sd.w));
    }
    #pragma unroll
    for (int h = 0; h < 4; ++h) red[h][t] = mx[h];
    __syncthreads();
    for (int s = 64; s > 0; s >>= 1) {
        if (t < s)
            #pragma unroll
            for (int h = 0; h < 4; ++h) red[h][t] = fmaxf(red[h][t], red[h][t + s]);
        __syncthreads();
    }
    if (t < 4) Mh[t] = red[t][0];
    __syncthreads();
    float m0 = Mh[0], m1 = Mh[1], m2 = Mh[2], m3 = Mh[3];

    // pass 1b: denom
    float sm[4] = {0.f, 0.f, 0.f, 0.f};
    for (int j = start + t; j < end; j += 128) {
        const float4 ss = *(const float4*)(s_src + csr_src[j] * 4);
        sm[0] += __expf(lrelu(ss.x + sd.x) - m0);
        sm[1] += __expf(lrelu(ss.y + sd.y) - m1);
        sm[2] += __expf(lrelu(ss.z + sd.z) - m2);
        sm[3] += __expf(lrelu(ss.w + sd.w) - m3);
    }
    __syncthreads();
    #pragma unroll
    for (int h = 0; h < 4; ++h) red[h][t] = sm[h];
    __syncthreads();
    for (int s = 64; s > 0; s >>= 1) {
        if (t < s)
            #pragma unroll
            for (int h = 0; h < 4; ++h) red[h][t] += red[h][t + s];
        __syncthreads();
    }
    if (t < 4) inv[t] = 1.f / red[t][0];
    __syncthreads();
    float i0 = inv[0], i1 = inv[1], i2 = inv[2], i3 = inv[3];

    // pass 2: alpha-weighted gather of xh[src], chunked through LDS
    float acc0 = 0.f, acc1 = 0.f, acc2 = 0.f, acc3 = 0.f;
    for (int c0 = start; c0 < end; c0 += 128) {
        int cnt = min(128, end - c0);
        __syncthreads();
        if (t < cnt) {
            int s = csr_src[c0 + t];
            csrc[t] = s;
            const float4 ss = *(const float4*)(s_src + s * 4);
            calpha[t][0] = __expf(lrelu(ss.x + sd.x) - m0) * i0;
            calpha[t][1] = __expf(lrelu(ss.y + sd.y) - m1) * i1;
            calpha[t][2] = __expf(lrelu(ss.z + sd.z) - m2) * i2;
            calpha[t][3] = __expf(lrelu(ss.w + sd.w) - m3) * i3;
        }
        __syncthreads();
        for (int jj = 0; jj < cnt; ++jj) {
            const float* xr = xh + (size_t)csrc[jj] * NCOLS;
            float a0 = calpha[jj][0], a1 = calpha[jj][1];
            float a2 = calpha[jj][2], a3 = calpha[jj][3];
            acc0 += a0 * xr[t];
            acc1 += a1 * xr[HID + t];
            acc2 += a2 * xr[2 * HID + t];
            acc3 += a3 * xr[3 * HID + t];
        }
    }
    float o = (acc0 + acc1 + acc2 + acc3) * 0.25f + bias[t];
    o = o * (gamma[t] * rsqrtf(1.f + 1e-5f)) + beta[t];
    h_out[(size_t)n * HID + t] = fmaxf(o, 0.f);
}

// ---------------- pooling (batch sorted -> run-length partial sums) ----------------
__global__ __launch_bounds__(128) void pool_kernel(const float* __restrict__ h,
                                                   const int* __restrict__ batch,
                                                   float* pooled, float* counts) {
    int t = threadIdx.x;
    int n0 = blockIdx.x * 256;
    int n1 = min(n0 + 256, N_NODES);
    if (n0 >= N_NODES) return;
    int cg = batch[n0];
    float acc = 0.f, cnt = 0.f;
    for (int n = n0; n < n1; ++n) {
        int g = batch[n];
        if (g != cg) {
            atomicAdd(&pooled[cg * HID + t], acc);
            if (t == 0) atomicAdd(&counts[cg], cnt);
            acc = 0.f; cnt = 0.f; cg = g;
        }
        acc += h[(size_t)n * HID + t];
        cnt += 1.f;
    }
    atomicAdd(&pooled[cg * HID + t], acc);
    if (t == 0) atomicAdd(&counts[cg], cnt);
}

// ---------------- head: mean-divide + fc1 + relu + fc2 ----------------
__global__ __launch_bounds__(128) void head_kernel(const float* __restrict__ pooled,
                                                   const float* __restrict__ counts,
                                                   const float* __restrict__ fc1_w,
                                                   const float* __restrict__ fc1_b,
                                                   const float* __restrict__ fc2_w,
                                                   const float* __restrict__ fc2_b,
                                                   float* __restrict__ out) {
    int gI = blockIdx.x;
    int t = threadIdx.x;
    __shared__ float p[HID], hb[HID];
    p[t] = pooled[gI * HID + t] / fmaxf(counts[gI], 1.f);
    __syncthreads();
    float a = fc1_b[t];
    #pragma unroll 4
    for (int k = 0; k < HID; ++k) a += p[k] * fc1_w[k * HID + t];
    hb[t] = fmaxf(a, 0.f);
    __syncthreads();
    if (t < OUTDIM) {
        float o = fc2_b[t];
        #pragma unroll 4
        for (int k = 0; k < HID; ++k) o += hb[k] * fc2_w[k * OUTDIM + t];
        out[gI * OUTDIM + t] = o;
    }
}

extern "C" void kernel_launch(void* const* d_in, const int* in_sizes, int n_in,
                              void* d_out, int out_size, void* d_ws, size_t ws_size,
                              hipStream_t stream) {
    const float* x     = (const float*)d_in[0];
    const int*   ei    = (const int*)d_in[1];
    const int*   batch = (const int*)d_in[2];
    const float* W[3]  = {(const float*)d_in[3],  (const float*)d_in[9],  (const float*)d_in[15]};
    const float* As[3] = {(const float*)d_in[4],  (const float*)d_in[10], (const float*)d_in[16]};
    const float* Ad[3] = {(const float*)d_in[5],  (const float*)d_in[11], (const float*)d_in[17]};
    const float* Bb[3] = {(const float*)d_in[6],  (const float*)d_in[12], (const float*)d_in[18]};
    const float* Gg[3] = {(const float*)d_in[7],  (const float*)d_in[13], (const float*)d_in[19]};
    const float* Be[3] = {(const float*)d_in[8],  (const float*)d_in[14], (const float*)d_in[20]};
    const float* fc1_w = (const float*)d_in[21];
    const float* fc1_b = (const float*)d_in[22];
    const float* fc2_w = (const float*)d_in[23];
    const float* fc2_b = (const float*)d_in[24];

    char* ws = (char*)d_ws;
    size_t off = 0;
    auto alloc = [&](size_t bytes) {
        void* p = ws + off;
        off = (off + bytes + 255) & ~(size_t)255;
        return p;
    };
    float* xh      = (float*)alloc((size_t)N_NODES * NCOLS * 4);
    float* hA      = (float*)alloc((size_t)N_NODES * HID * 4);
    float* hB      = (float*)alloc((size_t)N_NODES * HID * 4);
    float* ssrc    = (float*)alloc((size_t)N_NODES * HEADS * 4);
    float* sdst    = (float*)alloc((size_t)N_NODES * HEADS * 4);
    int*   deg     = (int*)alloc((size_t)N_NODES * 4);
    int*   offsets = (int*)alloc((size_t)(N_NODES + 1) * 4);
    int*   pos     = (int*)alloc((size_t)N_NODES * 4);
    int*   csr     = (int*)alloc((size_t)(N_EDGES + N_NODES) * 4);
    float* pooled  = (float*)alloc((size_t)NGROUPS * HID * 4);
    float* counts  = (float*)alloc((size_t)NGROUPS * 4);

    // CSR by dst (with self loops)
    deg_init_kernel<<<(N_NODES + 255) / 256, 256, 0, stream>>>(deg);
    deg_count_kernel<<<(N_EDGES + 255) / 256, 256, 0, stream>>>(ei, deg);
    scan_kernel<<<1, 1024, 0, stream>>>(deg, offsets, pos);
    scatter_kernel<<<(N_EDGES + N_NODES + 255) / 256, 256, 0, stream>>>(ei, pos, csr);

    // 3 GAT layers
    const float* hin = x;
    float* houts[3] = {hA, hB, hA};
    for (int l = 0; l < 3; ++l) {
        int K = (l == 0) ? FIN : HID;
        gemm_kernel<<<dim3(N_NODES / 64, NCOLS / 64), 256, 0, stream>>>(hin, W[l], xh, K);
        scores_kernel<<<(N_NODES + 3) / 4, 256, 0, stream>>>(xh, As[l], Ad[l], ssrc, sdst);
        aggregate_kernel<<<N_NODES, 128, 0, stream>>>(xh, ssrc, sdst, offsets, csr,
                                                      Bb[l], Gg[l], Be[l], houts[l]);
        hin = houts[l];
    }

    // global mean pool + MLP head
    hipMemsetAsync(pooled, 0, (size_t)NGROUPS * HID * 4, stream);
    hipMemsetAsync(counts, 0, (size_t)NGROUPS * 4, stream);
    pool_kernel<<<(N_NODES + 255) / 256, 128, 0, stream>>>(hin, batch, pooled, counts);
    head_kernel<<<NGROUPS, 128, 0, stream>>>(pooled, counts, fc1_w, fc1_b, fc2_w, fc2_b,
                                             (float*)d_out);
}

// Round 2
// 942.415 us; speedup vs baseline: 1.1900x; 1.1900x over previous
//
#include <hip/hip_runtime.h>
#include <hip/hip_fp16.h>
#include <math.h>

#define N_NODES 40000
#define N_EDGES 640000
#define FIN 64
#define HID 128
#define OUTDIM 64
#define HEADS 4
#define NGROUPS 64
#define NCOLS 512   // HEADS*HID

__device__ __forceinline__ float lrelu(float x) { return x > 0.f ? x : 0.2f * x; }

// ---------------- CSR build ----------------
__global__ void deg_init_kernel(int* deg) {
    int i = blockIdx.x * blockDim.x + threadIdx.x;
    if (i < N_NODES) deg[i] = 1;   // self loop
}

__global__ void deg_count_kernel(const int* __restrict__ ei, int* deg) {
    int e = blockIdx.x * blockDim.x + threadIdx.x;
    if (e < N_EDGES) atomicAdd(&deg[ei[N_EDGES + e]], 1);
}

__global__ void scan_kernel(const int* __restrict__ deg, int* offsets, int* pos) {
    __shared__ int buf[1024];
    __shared__ int carry_s;
    int t = threadIdx.x;
    if (t == 0) carry_s = 0;
    __syncthreads();
    for (int base = 0; base < N_NODES; base += 1024) {
        int v = (base + t < N_NODES) ? deg[base + t] : 0;
        buf[t] = v;
        __syncthreads();
        for (int off = 1; off < 1024; off <<= 1) {
            int y = (t >= off) ? buf[t - off] : 0;
            __syncthreads();
            buf[t] += y;
            __syncthreads();
        }
        int carry = carry_s;
        if (base + t < N_NODES) {
            int excl = carry + buf[t] - v;
            offsets[base + t] = excl;
            pos[base + t] = excl;
        }
        __syncthreads();
        if (t == 1023) carry_s = carry + buf[1023];
        __syncthreads();
    }
    if (t == 0) offsets[N_NODES] = carry_s;
}

__global__ void scatter_kernel(const int* __restrict__ ei, int* pos, int* csr_src) {
    int i = blockIdx.x * blockDim.x + threadIdx.x;
    if (i < N_EDGES) {
        int s = ei[i];
        int d = ei[N_EDGES + i];
        csr_src[atomicAdd(&pos[d], 1)] = s;
    } else if (i < N_EDGES + N_NODES) {
        int nn = i - N_EDGES;
        csr_src[atomicAdd(&pos[nn], 1)] = nn;
    }
}

// ---------------- GEMM: C[M,512] = A[M,K] @ B[K,512], fp32 math, fp16 store --------
__global__ __launch_bounds__(256) void gemm_kernel(const float* __restrict__ A,
                                                   const float* __restrict__ B,
                                                   __half* __restrict__ C, int K) {
    __shared__ float As[16][64];
    __shared__ float Bs[16][64];
    int bm = blockIdx.x * 64;
    int bn = blockIdx.y * 64;
    int tid = threadIdx.x;
    int tx = tid & 15, ty = tid >> 4;
    float acc[4][4] = {};
    for (int k0 = 0; k0 < K; k0 += 16) {
        #pragma unroll
        for (int i = tid; i < 64 * 16; i += 256) {
            int m = i >> 4, k = i & 15;
            As[k][m] = A[(size_t)(bm + m) * K + k0 + k];
        }
        #pragma unroll
        for (int i = tid; i < 16 * 64; i += 256) {
            int k = i >> 6, n = i & 63;
            Bs[k][n] = B[(size_t)(k0 + k) * NCOLS + bn + n];
        }
        __syncthreads();
        #pragma unroll
        for (int k = 0; k < 16; ++k) {
            float a[4], bb[4];
            #pragma unroll
            for (int i = 0; i < 4; ++i) a[i] = As[k][ty * 4 + i];
            #pragma unroll
            for (int j = 0; j < 4; ++j) bb[j] = Bs[k][tx * 4 + j];
            #pragma unroll
            for (int i = 0; i < 4; ++i)
                #pragma unroll
                for (int j = 0; j < 4; ++j)
                    acc[i][j] += a[i] * bb[j];
        }
        __syncthreads();
    }
    #pragma unroll
    for (int i = 0; i < 4; ++i) {
        int row = bm + ty * 4 + i;
        __half* cp = C + (size_t)row * NCOLS + bn + tx * 4;
        __half2 p0 = __floats2half2_rn(acc[i][0], acc[i][1]);
        __half2 p1 = __floats2half2_rn(acc[i][2], acc[i][3]);
        *(__half2*)(cp)     = p0;
        *(__half2*)(cp + 2) = p1;
    }
}

// ---------------- attention scores per node: s = <xh[n,h,:], a[h,:]> ----------------
__global__ __launch_bounds__(256) void scores_kernel(const __half* __restrict__ xh,
                                                     const float* __restrict__ a_s,
                                                     const float* __restrict__ a_d,
                                                     float* __restrict__ s_src,
                                                     float* __restrict__ s_dst) {
    int node = blockIdx.x * 4 + (threadIdx.x >> 6);
    int lane = threadIdx.x & 63;
    if (node >= N_NODES) return;
    const __half* row = xh + (size_t)node * NCOLS;
    float ps[HEADS], pd[HEADS];
    #pragma unroll
    for (int h = 0; h < HEADS; ++h) {
        float v0 = __half2float(row[h * HID + lane]);
        float v1 = __half2float(row[h * HID + 64 + lane]);
        ps[h] = v0 * a_s[h * HID + lane] + v1 * a_s[h * HID + 64 + lane];
        pd[h] = v0 * a_d[h * HID + lane] + v1 * a_d[h * HID + 64 + lane];
    }
    #pragma unroll
    for (int off = 32; off > 0; off >>= 1) {
        #pragma unroll
        for (int h = 0; h < HEADS; ++h) {
            ps[h] += __shfl_down(ps[h], off);
            pd[h] += __shfl_down(pd[h], off);
        }
    }
    if (lane == 0) {
        #pragma unroll
        for (int h = 0; h < HEADS; ++h) {
            s_src[node * HEADS + h] = ps[h];
            s_dst[node * HEADS + h] = pd[h];
        }
    }
}

// ---- per-dst softmax + weighted fp16 gather + head-mean + bias + BN + ReLU --------
// 256 threads: head h = t>>6, half2 channel-pair c2 = t&63 (channels 2c2, 2c2+1)
__global__ __launch_bounds__(256) void aggregate_kernel(const __half* __restrict__ xh,
                                                        const float* __restrict__ s_src,
                                                        const float* __restrict__ s_dst,
                                                        const int* __restrict__ offsets,
                                                        const int* __restrict__ csr_src,
                                                        const float* __restrict__ bias,
                                                        const float* __restrict__ gamma,
                                                        const float* __restrict__ beta,
                                                        float* __restrict__ h_out) {
    int n = blockIdx.x;
    int t = threadIdx.x;
    int h = t >> 6;
    int c2 = t & 63;
    int lane = t & 63;
    int wid = t >> 6;
    int start = offsets[n], end = offsets[n + 1];
    const float4 sd = *(const float4*)(s_dst + n * 4);

    __shared__ float wred[4][4];       // [wave][head]
    __shared__ float Mh[4], inv[4];
    __shared__ int   csrc[128];
    __shared__ float calpha[128][4];
    __shared__ float sum2[4][64][2];

    // pass 1a: per-head max of leaky_relu(s_src[src]+s_dst[n])
    float mx[4] = {-1e30f, -1e30f, -1e30f, -1e30f};
    for (int j = start + t; j < end; j += 256) {
        const float4 ss = *(const float4*)(s_src + csr_src[j] * 4);
        mx[0] = fmaxf(mx[0], lrelu(ss.x + sd.x));
        mx[1] = fmaxf(mx[1], lrelu(ss.y + sd.y));
        mx[2] = fmaxf(mx[2], lrelu(ss.z + sd.z));
        mx[3] = fmaxf(mx[3], lrelu(ss.w + sd.w));
    }
    #pragma unroll
    for (int off = 32; off > 0; off >>= 1) {
        #pragma unroll
        for (int k = 0; k < 4; ++k) mx[k] = fmaxf(mx[k], __shfl_down(mx[k], off));
    }
    if (lane == 0) {
        #pragma unroll
        for (int k = 0; k < 4; ++k) wred[wid][k] = mx[k];
    }
    __syncthreads();
    if (t < 4) Mh[t] = fmaxf(fmaxf(wred[0][t], wred[1][t]), fmaxf(wred[2][t], wred[3][t]));
    __syncthreads();
    float m0 = Mh[0], m1 = Mh[1], m2 = Mh[2], m3 = Mh[3];

    // pass 1b: denom
    float sm[4] = {0.f, 0.f, 0.f, 0.f};
    for (int j = start + t; j < end; j += 256) {
        const float4 ss = *(const float4*)(s_src + csr_src[j] * 4);
        sm[0] += __expf(lrelu(ss.x + sd.x) - m0);
        sm[1] += __expf(lrelu(ss.y + sd.y) - m1);
        sm[2] += __expf(lrelu(ss.z + sd.z) - m2);
        sm[3] += __expf(lrelu(ss.w + sd.w) - m3);
    }
    #pragma unroll
    for (int off = 32; off > 0; off >>= 1) {
        #pragma unroll
        for (int k = 0; k < 4; ++k) sm[k] += __shfl_down(sm[k], off);
    }
    __syncthreads();  // wred reuse
    if (lane == 0) {
        #pragma unroll
        for (int k = 0; k < 4; ++k) wred[wid][k] = sm[k];
    }
    __syncthreads();
    if (t < 4) inv[t] = 1.f / (wred[0][t] + wred[1][t] + wred[2][t] + wred[3][t]);
    __syncthreads();
    float i0 = inv[0], i1 = inv[1], i2 = inv[2], i3 = inv[3];

    // pass 2: alpha-weighted gather of fp16 xh[src], chunked through LDS
    float2 acc = {0.f, 0.f};
    const int coff = h * HID + 2 * c2;
    for (int c0 = start; c0 < end; c0 += 128) {
        int cnt = min(128, end - c0);
        __syncthreads();
        if (t < cnt) {
            int s = csr_src[c0 + t];
            csrc[t] = s;
            const float4 ss = *(const float4*)(s_src + s * 4);
            calpha[t][0] = __expf(lrelu(ss.x + sd.x) - m0) * i0;
            calpha[t][1] = __expf(lrelu(ss.y + sd.y) - m1) * i1;
            calpha[t][2] = __expf(lrelu(ss.z + sd.z) - m2) * i2;
            calpha[t][3] = __expf(lrelu(ss.w + sd.w) - m3) * i3;
        }
        __syncthreads();
        for (int jj = 0; jj < cnt; ++jj) {
            const __half2 v = *(const __half2*)(xh + (size_t)csrc[jj] * NCOLS + coff);
            float2 vf = __half22float2(v);
            float a = calpha[jj][h];
            acc.x += a * vf.x;
            acc.y += a * vf.y;
        }
    }
    sum2[h][c2][0] = acc.x;
    sum2[h][c2][1] = acc.y;
    __syncthreads();
    if (t < HID) {
        int c = t, cc2 = c >> 1, par = c & 1;
        float o = (sum2[0][cc2][par] + sum2[1][cc2][par] +
                   sum2[2][cc2][par] + sum2[3][cc2][par]) * 0.25f + bias[c];
        o = o * (gamma[c] * rsqrtf(1.f + 1e-5f)) + beta[c];
        h_out[(size_t)n * HID + c] = fmaxf(o, 0.f);
    }
}

// ---------------- pooling (batch sorted -> run-length partial sums) ----------------
__global__ __launch_bounds__(128) void pool_kernel(const float* __restrict__ h,
                                                   const int* __restrict__ batch,
                                                   float* pooled, float* counts) {
    int t = threadIdx.x;
    int n0 = blockIdx.x * 256;
    int n1 = min(n0 + 256, N_NODES);
    if (n0 >= N_NODES) return;
    int cg = batch[n0];
    float acc = 0.f, cnt = 0.f;
    for (int n = n0; n < n1; ++n) {
        int g = batch[n];
        if (g != cg) {
            atomicAdd(&pooled[cg * HID + t], acc);
            if (t == 0) atomicAdd(&counts[cg], cnt);
            acc = 0.f; cnt = 0.f; cg = g;
        }
        acc += h[(size_t)n * HID + t];
        cnt += 1.f;
    }
    atomicAdd(&pooled[cg * HID + t], acc);
    if (t == 0) atomicAdd(&counts[cg], cnt);
}

// ---------------- head: mean-divide + fc1 + relu + fc2 ----------------
__global__ __launch_bounds__(128) void head_kernel(const float* __restrict__ pooled,
                                                   const float* __restrict__ counts,
                                                   const float* __restrict__ fc1_w,
                                                   const float* __restrict__ fc1_b,
                                                   const float* __restrict__ fc2_w,
                                                   const float* __restrict__ fc2_b,
                                                   float* __restrict__ out) {
    int gI = blockIdx.x;
    int t = threadIdx.x;
    __shared__ float p[HID], hb[HID];
    p[t] = pooled[gI * HID + t] / fmaxf(counts[gI], 1.f);
    __syncthreads();
    float a = fc1_b[t];
    #pragma unroll 4
    for (int k = 0; k < HID; ++k) a += p[k] * fc1_w[k * HID + t];
    hb[t] = fmaxf(a, 0.f);
    __syncthreads();
    if (t < OUTDIM) {
        float o = fc2_b[t];
        #pragma unroll 4
        for (int k = 0; k < HID; ++k) o += hb[k] * fc2_w[k * OUTDIM + t];
        out[gI * OUTDIM + t] = o;
    }
}

extern "C" void kernel_launch(void* const* d_in, const int* in_sizes, int n_in,
                              void* d_out, int out_size, void* d_ws, size_t ws_size,
                              hipStream_t stream) {
    const float* x     = (const float*)d_in[0];
    const int*   ei    = (const int*)d_in[1];
    const int*   batch = (const int*)d_in[2];
    const float* W[3]  = {(const float*)d_in[3],  (const float*)d_in[9],  (const float*)d_in[15]};
    const float* As[3] = {(const float*)d_in[4],  (const float*)d_in[10], (const float*)d_in[16]};
    const float* Ad[3] = {(const float*)d_in[5],  (const float*)d_in[11], (const float*)d_in[17]};
    const float* Bb[3] = {(const float*)d_in[6],  (const float*)d_in[12], (const float*)d_in[18]};
    const float* Gg[3] = {(const float*)d_in[7],  (const float*)d_in[13], (const float*)d_in[19]};
    const float* Be[3] = {(const float*)d_in[8],  (const float*)d_in[14], (const float*)d_in[20]};
    const float* fc1_w = (const float*)d_in[21];
    const float* fc1_b = (const float*)d_in[22];
    const float* fc2_w = (const float*)d_in[23];
    const float* fc2_b = (const float*)d_in[24];

    char* ws = (char*)d_ws;
    size_t off = 0;
    auto alloc = [&](size_t bytes) {
        void* p = ws + off;
        off = (off + bytes + 255) & ~(size_t)255;
        return p;
    };
    __half* xh     = (__half*)alloc((size_t)N_NODES * NCOLS * 2);
    float* hA      = (float*)alloc((size_t)N_NODES * HID * 4);
    float* hB      = (float*)alloc((size_t)N_NODES * HID * 4);
    float* ssrc    = (float*)alloc((size_t)N_NODES * HEADS * 4);
    float* sdst    = (float*)alloc((size_t)N_NODES * HEADS * 4);
    int*   deg     = (int*)alloc((size_t)N_NODES * 4);
    int*   offsets = (int*)alloc((size_t)(N_NODES + 1) * 4);
    int*   pos     = (int*)alloc((size_t)N_NODES * 4);
    int*   csr     = (int*)alloc((size_t)(N_EDGES + N_NODES) * 4);
    float* pooled  = (float*)alloc((size_t)NGROUPS * HID * 4);
    float* counts  = (float*)alloc((size_t)NGROUPS * 4);

    // CSR by dst (with self loops)
    deg_init_kernel<<<(N_NODES + 255) / 256, 256, 0, stream>>>(deg);
    deg_count_kernel<<<(N_EDGES + 255) / 256, 256, 0, stream>>>(ei, deg);
    scan_kernel<<<1, 1024, 0, stream>>>(deg, offsets, pos);
    scatter_kernel<<<(N_EDGES + N_NODES + 255) / 256, 256, 0, stream>>>(ei, pos, csr);

    // 3 GAT layers
    const float* hin = x;
    float* houts[3] = {hA, hB, hA};
    for (int l = 0; l < 3; ++l) {
        int K = (l == 0) ? FIN : HID;
        gemm_kernel<<<dim3(N_NODES / 64, NCOLS / 64), 256, 0, stream>>>(hin, W[l], xh, K);
        scores_kernel<<<(N_NODES + 3) / 4, 256, 0, stream>>>(xh, As[l], Ad[l], ssrc, sdst);
        aggregate_kernel<<<N_NODES, 256, 0, stream>>>(xh, ssrc, sdst, offsets, csr,
                                                      Bb[l], Gg[l], Be[l], houts[l]);
        hin = houts[l];
    }

    // global mean pool + MLP head
    hipMemsetAsync(pooled, 0, (size_t)NGROUPS * HID * 4, stream);
    hipMemsetAsync(counts, 0, (size_t)NGROUPS * 4, stream);
    pool_kernel<<<(N_NODES + 255) / 256, 128, 0, stream>>>(hin, batch, pooled, counts);
    head_kernel<<<NGROUPS, 128, 0, stream>>>(pooled, counts, fc1_w, fc1_b, fc2_w, fc2_b,
                                             (float*)d_out);
}

// Round 4
// 776.385 us; speedup vs baseline: 1.4444x; 1.2138x over previous
//
#include <hip/hip_runtime.h>
#include <hip/hip_fp16.h>
#include <math.h>

#define N_NODES 40000
#define N_EDGES 640000
#define FIN 64
#define HID 128
#define OUTDIM 64
#define HEADS 4
#define NGROUPS 64
#define NCOLS 512   // HEADS*HID

typedef _Float16 half8 __attribute__((ext_vector_type(8)));
typedef float f32x4 __attribute__((ext_vector_type(4)));

__device__ __forceinline__ float lrelu(float x) { return x > 0.f ? x : 0.2f * x; }

// ---------------- fp32 -> fp16 convert ----------------
__global__ void f32to16_kernel(const float* __restrict__ src, __half* __restrict__ dst, int n) {
    int i4 = (blockIdx.x * blockDim.x + threadIdx.x) * 4;
    if (i4 < n) {
        float4 v = *(const float4*)(src + i4);
        __half2 a = __floats2half2_rn(v.x, v.y);
        __half2 b = __floats2half2_rn(v.z, v.w);
        *(__half2*)(dst + i4)     = a;
        *(__half2*)(dst + i4 + 2) = b;
    }
}

// ---------------- CSR build ----------------
__global__ void deg_init_kernel(int* deg) {
    int i = blockIdx.x * blockDim.x + threadIdx.x;
    if (i < N_NODES) deg[i] = 1;   // self loop
}

__global__ void deg_count_kernel(const int* __restrict__ ei, int* deg) {
    int e = blockIdx.x * blockDim.x + threadIdx.x;
    if (e < N_EDGES) atomicAdd(&deg[ei[N_EDGES + e]], 1);
}

__global__ void scan1_kernel(const int* __restrict__ deg, int* offsets, int* partial) {
    __shared__ int buf[256];
    int t = threadIdx.x;
    int i = blockIdx.x * 256 + t;
    int v = (i < N_NODES) ? deg[i] : 0;
    buf[t] = v;
    __syncthreads();
    for (int off = 1; off < 256; off <<= 1) {
        int y = (t >= off) ? buf[t - off] : 0;
        __syncthreads();
        buf[t] += y;
        __syncthreads();
    }
    if (i < N_NODES) offsets[i] = buf[t] - v;       // local exclusive
    if (t == 255) partial[blockIdx.x] = buf[255];
}

__global__ void scan2_kernel(int* partial, int nb) {
    __shared__ int buf[256];
    int t = threadIdx.x;
    int v = (t < nb) ? partial[t] : 0;
    buf[t] = v;
    __syncthreads();
    for (int off = 1; off < 256; off <<= 1) {
        int y = (t >= off) ? buf[t - off] : 0;
        __syncthreads();
        buf[t] += y;
        __syncthreads();
    }
    if (t < nb) partial[t] = buf[t] - v;            // exclusive block prefix
}

__global__ void scan3_kernel(int* offsets, int* pos, const int* __restrict__ partial) {
    int i = blockIdx.x * 256 + threadIdx.x;
    if (i < N_NODES) {
        int o = offsets[i] + partial[i >> 8];
        offsets[i] = o;
        pos[i] = o;
    }
    if (i == 0) offsets[N_NODES] = N_EDGES + N_NODES;
}

__global__ void scatter_kernel(const int* __restrict__ ei, int* pos, int* csr_src) {
    int i = blockIdx.x * blockDim.x + threadIdx.x;
    if (i < N_EDGES) {
        int s = ei[i];
        int d = ei[N_EDGES + i];
        csr_src[atomicAdd(&pos[d], 1)] = s;
    } else if (i < N_EDGES + N_NODES) {
        int nn = i - N_EDGES;
        csr_src[atomicAdd(&pos[nn], 1)] = nn;
    }
}

// ------- MFMA GEMM: C[M,512] = A16[M,K] @ W16[K,512], fp16 in, fp32 acc, fp16 out ---
// 64x64 block tile, 4 waves each 32x32. Full A tile + full B panel staged ONCE
// (both [row/col][k], stride 136 halves = 272B keeps 16B alignment, 2-way bank alias).
// k-loop is pure ds_read_b128 + MFMA, no barriers. FIX vs r3: frag index is k0+lk.
__global__ __launch_bounds__(256) void gemm_f16_kernel(const __half* __restrict__ A,
                                                       const __half* __restrict__ W16,
                                                       __half* __restrict__ C, int K) {
    __shared__ _Float16 As[64][136];   // [row][k]
    __shared__ _Float16 Bs[64][136];   // [col][k]
    int bm = blockIdx.x * 64;
    int bn = blockIdx.y * 64;
    int t = threadIdx.x;
    int lane = t & 63;
    int w = t >> 6;
    int wm = w >> 1, wn = w & 1;
    int lr = lane & 15;
    int lk = (lane >> 4) * 8;

    // stage full A tile [64][K]
    if (K == 64) {
        int row = t >> 3, k8 = (t & 7) * 8;
        #pragma unroll
        for (int rr = 0; rr < 64; rr += 32) {
            uint4 av = *(const uint4*)(A + (size_t)(bm + row + rr) * 64 + k8);
            *(uint4*)&As[row + rr][k8] = av;
        }
    } else {  // K == 128
        int row = t >> 4, k8 = (t & 15) * 8;
        #pragma unroll
        for (int rr = 0; rr < 64; rr += 16) {
            uint4 av = *(const uint4*)(A + (size_t)(bm + row + rr) * 128 + k8);
            *(uint4*)&As[row + rr][k8] = av;
        }
    }
    // stage B panel transposed: Bs[col][k]
    {
        int col = t & 63;
        int kb = (t >> 6) * 8;
        for (int k8 = kb; k8 < K; k8 += 32) {
            const __half* wp = W16 + (size_t)k8 * NCOLS + bn + col;
            uint u0 = (uint)__half_as_ushort(wp[0])         | ((uint)__half_as_ushort(wp[NCOLS])     << 16);
            uint u1 = (uint)__half_as_ushort(wp[2 * NCOLS]) | ((uint)__half_as_ushort(wp[3 * NCOLS]) << 16);
            uint u2 = (uint)__half_as_ushort(wp[4 * NCOLS]) | ((uint)__half_as_ushort(wp[5 * NCOLS]) << 16);
            uint u3 = (uint)__half_as_ushort(wp[6 * NCOLS]) | ((uint)__half_as_ushort(wp[7 * NCOLS]) << 16);
            uint4 uu = {u0, u1, u2, u3};
            *(uint4*)&Bs[col][k8] = uu;
        }
    }
    __syncthreads();

    f32x4 acc[2][2] = {};
    for (int k0 = 0; k0 < K; k0 += 32) {
        half8 af[2], bf[2];
        #pragma unroll
        for (int m = 0; m < 2; ++m) af[m] = *(const half8*)&As[wm * 32 + m * 16 + lr][k0 + lk];
        #pragma unroll
        for (int nn = 0; nn < 2; ++nn) bf[nn] = *(const half8*)&Bs[wn * 32 + nn * 16 + lr][k0 + lk];
        #pragma unroll
        for (int m = 0; m < 2; ++m)
            #pragma unroll
            for (int nn = 0; nn < 2; ++nn)
                acc[m][nn] = __builtin_amdgcn_mfma_f32_16x16x32_f16(af[m], bf[nn], acc[m][nn], 0, 0, 0);
    }

    int lg = lane >> 4;
    #pragma unroll
    for (int m = 0; m < 2; ++m) {
        #pragma unroll
        for (int nn = 0; nn < 2; ++nn) {
            int col = bn + wn * 32 + nn * 16 + lr;
            #pragma unroll
            for (int r = 0; r < 4; ++r) {
                int row = bm + wm * 32 + m * 16 + lg * 4 + r;
                C[(size_t)row * NCOLS + col] = __float2half(acc[m][nn][r]);
            }
        }
    }
}

// ---------------- attention scores per node: s = <xh[n,h,:], a[h,:]> ----------------
__global__ __launch_bounds__(256) void scores_kernel(const __half* __restrict__ xh,
                                                     const float* __restrict__ a_s,
                                                     const float* __restrict__ a_d,
                                                     float* __restrict__ s_src,
                                                     float* __restrict__ s_dst) {
    int node = blockIdx.x * 4 + (threadIdx.x >> 6);
    int lane = threadIdx.x & 63;
    if (node >= N_NODES) return;
    const __half* row = xh + (size_t)node * NCOLS;
    float ps[HEADS], pd[HEADS];
    #pragma unroll
    for (int h = 0; h < HEADS; ++h) {
        float v0 = __half2float(row[h * HID + lane]);
        float v1 = __half2float(row[h * HID + 64 + lane]);
        ps[h] = v0 * a_s[h * HID + lane] + v1 * a_s[h * HID + 64 + lane];
        pd[h] = v0 * a_d[h * HID + lane] + v1 * a_d[h * HID + 64 + lane];
    }
    #pragma unroll
    for (int off = 32; off > 0; off >>= 1) {
        #pragma unroll
        for (int h = 0; h < HEADS; ++h) {
            ps[h] += __shfl_down(ps[h], off);
            pd[h] += __shfl_down(pd[h], off);
        }
    }
    if (lane == 0) {
        #pragma unroll
        for (int h = 0; h < HEADS; ++h) {
            s_src[node * HEADS + h] = ps[h];
            s_dst[node * HEADS + h] = pd[h];
        }
    }
}

// ---- per-dst softmax + weighted fp16 gather + head-mean + bias + BN + ReLU --------
// pass2: 2 edges in flight (half = t>>7), 8B loads: thread covers elems tq*4..tq*4+3
__global__ __launch_bounds__(256) void aggregate_kernel(const __half* __restrict__ xh,
                                                        const float* __restrict__ s_src,
                                                        const float* __restrict__ s_dst,
                                                        const int* __restrict__ offsets,
                                                        const int* __restrict__ csr_src,
                                                        const float* __restrict__ bias,
                                                        const float* __restrict__ gamma,
                                                        const float* __restrict__ beta,
                                                        float* __restrict__ h_out,
                                                        __half* __restrict__ h16out) {
    int n = blockIdx.x;
    int t = threadIdx.x;
    int lane = t & 63;
    int wid = t >> 6;
    int start = offsets[n], end = offsets[n + 1];
    const float4 sd = *(const float4*)(s_dst + n * 4);

    __shared__ float wred[4][4];
    __shared__ float Mh[4], inv[4];
    __shared__ int   rowoff[132];
    __shared__ float calpha[132][4];
    __shared__ float fsum[2][512];

    // pass 1a: per-head max of leaky_relu(s_src[src]+s_dst[n])
    float mx[4] = {-1e30f, -1e30f, -1e30f, -1e30f};
    for (int j = start + t; j < end; j += 256) {
        const float4 ss = *(const float4*)(s_src + csr_src[j] * 4);
        mx[0] = fmaxf(mx[0], lrelu(ss.x + sd.x));
        mx[1] = fmaxf(mx[1], lrelu(ss.y + sd.y));
        mx[2] = fmaxf(mx[2], lrelu(ss.z + sd.z));
        mx[3] = fmaxf(mx[3], lrelu(ss.w + sd.w));
    }
    #pragma unroll
    for (int off = 32; off > 0; off >>= 1) {
        #pragma unroll
        for (int k = 0; k < 4; ++k) mx[k] = fmaxf(mx[k], __shfl_down(mx[k], off));
    }
    if (lane == 0) {
        #pragma unroll
        for (int k = 0; k < 4; ++k) wred[wid][k] = mx[k];
    }
    __syncthreads();
    if (t < 4) Mh[t] = fmaxf(fmaxf(wred[0][t], wred[1][t]), fmaxf(wred[2][t], wred[3][t]));
    __syncthreads();
    float m0 = Mh[0], m1 = Mh[1], m2 = Mh[2], m3 = Mh[3];

    // pass 1b: denom
    float sm[4] = {0.f, 0.f, 0.f, 0.f};
    for (int j = start + t; j < end; j += 256) {
        const float4 ss = *(const float4*)(s_src + csr_src[j] * 4);
        sm[0] += __expf(lrelu(ss.x + sd.x) - m0);
        sm[1] += __expf(lrelu(ss.y + sd.y) - m1);
        sm[2] += __expf(lrelu(ss.z + sd.z) - m2);
        sm[3] += __expf(lrelu(ss.w + sd.w) - m3);
    }
    #pragma unroll
    for (int off = 32; off > 0; off >>= 1) {
        #pragma unroll
        for (int k = 0; k < 4; ++k) sm[k] += __shfl_down(sm[k], off);
    }
    __syncthreads();
    if (lane == 0) {
        #pragma unroll
        for (int k = 0; k < 4; ++k) wred[wid][k] = sm[k];
    }
    __syncthreads();
    if (t < 4) inv[t] = 1.f / (wred[0][t] + wred[1][t] + wred[2][t] + wred[3][t]);
    __syncthreads();
    float i0 = inv[0], i1 = inv[1], i2 = inv[2], i3 = inv[3];

    // pass 2
    int tq = t & 127;
    int half = t >> 7;
    int hh = tq >> 5;
    f32x4 acc = {0.f, 0.f, 0.f, 0.f};
    const char* base = (const char*)xh + tq * 8;
    for (int c0 = start; c0 < end; c0 += 128) {
        int cnt = min(128, end - c0);
        __syncthreads();
        if (t < cnt) {
            int s = csr_src[c0 + t];
            rowoff[t] = s << 10;   // byte offset: s * NCOLS * 2
            const float4 ss = *(const float4*)(s_src + s * 4);
            calpha[t][0] = __expf(lrelu(ss.x + sd.x) - m0) * i0;
            calpha[t][1] = __expf(lrelu(ss.y + sd.y) - m1) * i1;
            calpha[t][2] = __expf(lrelu(ss.z + sd.z) - m2) * i2;
            calpha[t][3] = __expf(lrelu(ss.w + sd.w) - m3) * i3;
        }
        if (t == cnt) {
            rowoff[t] = 0;
            calpha[t][0] = 0.f; calpha[t][1] = 0.f; calpha[t][2] = 0.f; calpha[t][3] = 0.f;
        }
        __syncthreads();
        for (int jj = 0; jj < cnt; jj += 2) {
            int e = jj + half;
            float a = calpha[e][hh];
            uint2 u = *(const uint2*)(base + rowoff[e]);
            __half2 v0 = *(__half2*)&u.x;
            __half2 v1 = *(__half2*)&u.y;
            float2 f0 = __half22float2(v0);
            float2 f1 = __half22float2(v1);
            acc[0] += a * f0.x;
            acc[1] += a * f0.y;
            acc[2] += a * f1.x;
            acc[3] += a * f1.y;
        }
    }
    *(f32x4*)&fsum[half][tq * 4] = acc;
    __syncthreads();
    if (t < HID) {
        float o = 0.f;
        #pragma unroll
        for (int h2 = 0; h2 < 4; ++h2)
            o += fsum[0][h2 * 128 + t] + fsum[1][h2 * 128 + t];
        o = o * 0.25f + bias[t];
        o = o * (gamma[t] * rsqrtf(1.f + 1e-5f)) + beta[t];
        o = fmaxf(o, 0.f);
        h_out[(size_t)n * HID + t] = o;
        h16out[(size_t)n * HID + t] = __float2half(o);
    }
}

// ---------------- pooling (batch sorted -> run-length partial sums) ----------------
__global__ __launch_bounds__(128) void pool_kernel(const float* __restrict__ h,
                                                   const int* __restrict__ batch,
                                                   float* pooled, float* counts) {
    int t = threadIdx.x;
    int n0 = blockIdx.x * 256;
    int n1 = min(n0 + 256, N_NODES);
    if (n0 >= N_NODES) return;
    int cg = batch[n0];
    float acc = 0.f, cnt = 0.f;
    for (int n = n0; n < n1; ++n) {
        int g = batch[n];
        if (g != cg) {
            atomicAdd(&pooled[cg * HID + t], acc);
            if (t == 0) atomicAdd(&counts[cg], cnt);
            acc = 0.f; cnt = 0.f; cg = g;
        }
        acc += h[(size_t)n * HID + t];
        cnt += 1.f;
    }
    atomicAdd(&pooled[cg * HID + t], acc);
    if (t == 0) atomicAdd(&counts[cg], cnt);
}

// ---------------- head: mean-divide + fc1 + relu + fc2 ----------------
__global__ __launch_bounds__(128) void head_kernel(const float* __restrict__ pooled,
                                                   const float* __restrict__ counts,
                                                   const float* __restrict__ fc1_w,
                                                   const float* __restrict__ fc1_b,
                                                   const float* __restrict__ fc2_w,
                                                   const float* __restrict__ fc2_b,
                                                   float* __restrict__ out) {
    int gI = blockIdx.x;
    int t = threadIdx.x;
    __shared__ float p[HID], hb[HID];
    p[t] = pooled[gI * HID + t] / fmaxf(counts[gI], 1.f);
    __syncthreads();
    float a = fc1_b[t];
    #pragma unroll 4
    for (int k = 0; k < HID; ++k) a += p[k] * fc1_w[k * HID + t];
    hb[t] = fmaxf(a, 0.f);
    __syncthreads();
    if (t < OUTDIM) {
        float o = fc2_b[t];
        #pragma unroll 4
        for (int k = 0; k < HID; ++k) o += hb[k] * fc2_w[k * OUTDIM + t];
        out[gI * OUTDIM + t] = o;
    }
}

extern "C" void kernel_launch(void* const* d_in, const int* in_sizes, int n_in,
                              void* d_out, int out_size, void* d_ws, size_t ws_size,
                              hipStream_t stream) {
    const float* x     = (const float*)d_in[0];
    const int*   ei    = (const int*)d_in[1];
    const int*   batch = (const int*)d_in[2];
    const float* W[3]  = {(const float*)d_in[3],  (const float*)d_in[9],  (const float*)d_in[15]};
    const float* As[3] = {(const float*)d_in[4],  (const float*)d_in[10], (const float*)d_in[16]};
    const float* Ad[3] = {(const float*)d_in[5],  (const float*)d_in[11], (const float*)d_in[17]};
    const float* Bb[3] = {(const float*)d_in[6],  (const float*)d_in[12], (const float*)d_in[18]};
    const float* Gg[3] = {(const float*)d_in[7],  (const float*)d_in[13], (const float*)d_in[19]};
    const float* Be[3] = {(const float*)d_in[8],  (const float*)d_in[14], (const float*)d_in[20]};
    const float* fc1_w = (const float*)d_in[21];
    const float* fc1_b = (const float*)d_in[22];
    const float* fc2_w = (const float*)d_in[23];
    const float* fc2_b = (const float*)d_in[24];

    char* ws = (char*)d_ws;
    size_t off = 0;
    auto alloc = [&](size_t bytes) {
        void* p = ws + off;
        off = (off + bytes + 255) & ~(size_t)255;
        return p;
    };
    __half* xh     = (__half*)alloc((size_t)N_NODES * NCOLS * 2);
    __half* x16    = (__half*)alloc((size_t)N_NODES * FIN * 2);
    __half* h16    = (__half*)alloc((size_t)N_NODES * HID * 2);
    __half* W16[3];
    W16[0] = (__half*)alloc((size_t)FIN * NCOLS * 2);
    W16[1] = (__half*)alloc((size_t)HID * NCOLS * 2);
    W16[2] = (__half*)alloc((size_t)HID * NCOLS * 2);
    float* hA      = (float*)alloc((size_t)N_NODES * HID * 4);
    float* ssrc    = (float*)alloc((size_t)N_NODES * HEADS * 4);
    float* sdst    = (float*)alloc((size_t)N_NODES * HEADS * 4);
    int*   deg     = (int*)alloc((size_t)N_NODES * 4);
    int*   offsets = (int*)alloc((size_t)(N_NODES + 1) * 4);
    int*   pos     = (int*)alloc((size_t)N_NODES * 4);
    int*   partial = (int*)alloc((size_t)256 * 4);
    int*   csr     = (int*)alloc((size_t)(N_EDGES + N_NODES) * 4);
    float* pooled  = (float*)alloc((size_t)NGROUPS * HID * 4);
    float* counts  = (float*)alloc((size_t)NGROUPS * 4);

    // fp16 conversions
    f32to16_kernel<<<(N_NODES * FIN / 4 + 255) / 256, 256, 0, stream>>>(x, x16, N_NODES * FIN);
    f32to16_kernel<<<(FIN * NCOLS / 4 + 255) / 256, 256, 0, stream>>>(W[0], W16[0], FIN * NCOLS);
    f32to16_kernel<<<(HID * NCOLS / 4 + 255) / 256, 256, 0, stream>>>(W[1], W16[1], HID * NCOLS);
    f32to16_kernel<<<(HID * NCOLS / 4 + 255) / 256, 256, 0, stream>>>(W[2], W16[2], HID * NCOLS);

    // CSR by dst (with self loops)
    const int NB = (N_NODES + 255) / 256;   // 157
    deg_init_kernel<<<NB, 256, 0, stream>>>(deg);
    deg_count_kernel<<<(N_EDGES + 255) / 256, 256, 0, stream>>>(ei, deg);
    scan1_kernel<<<NB, 256, 0, stream>>>(deg, offsets, partial);
    scan2_kernel<<<1, 256, 0, stream>>>(partial, NB);
    scan3_kernel<<<NB, 256, 0, stream>>>(offsets, pos, partial);
    scatter_kernel<<<(N_EDGES + N_NODES + 255) / 256, 256, 0, stream>>>(ei, pos, csr);

    // 3 GAT layers
    const __half* Ain = x16;
    for (int l = 0; l < 3; ++l) {
        int K = (l == 0) ? FIN : HID;
        gemm_f16_kernel<<<dim3(N_NODES / 64, NCOLS / 64), 256, 0, stream>>>(Ain, W16[l], xh, K);
        scores_kernel<<<(N_NODES + 3) / 4, 256, 0, stream>>>(xh, As[l], Ad[l], ssrc, sdst);
        aggregate_kernel<<<N_NODES, 256, 0, stream>>>(xh, ssrc, sdst, offsets, csr,
                                                      Bb[l], Gg[l], Be[l], hA, h16);
        Ain = h16;
    }

    // global mean pool + MLP head
    hipMemsetAsync(pooled, 0, (size_t)NGROUPS * HID * 4, stream);
    hipMemsetAsync(counts, 0, (size_t)NGROUPS * 4, stream);
    pool_kernel<<<(N_NODES + 255) / 256, 128, 0, stream>>>(hA, batch, pooled, counts);
    head_kernel<<<NGROUPS, 128, 0, stream>>>(pooled, counts, fc1_w, fc1_b, fc2_w, fc2_b,
                                             (float*)d_out);
}

// Round 5
// 591.963 us; speedup vs baseline: 1.8944x; 1.3115x over previous
//
#include <hip/hip_runtime.h>
#include <hip/hip_fp16.h>
#include <math.h>

#define N_NODES 40000
#define N_EDGES 640000
#define FIN 64
#define HID 128
#define OUTDIM 64
#define HEADS 4
#define NGROUPS 64
#define NCOLS 512   // HEADS*HID

typedef _Float16 half8 __attribute__((ext_vector_type(8)));
typedef float f32x4 __attribute__((ext_vector_type(4)));

__device__ __forceinline__ float lrelu(float x) { return x > 0.f ? x : 0.2f * x; }

__device__ __forceinline__ void wave_lds_fence() {
    asm volatile("s_waitcnt lgkmcnt(0)" ::: "memory");
}

// ---------------- fp32 -> fp16 convert ----------------
__global__ void f32to16_kernel(const float* __restrict__ src, __half* __restrict__ dst, int n) {
    int i4 = (blockIdx.x * blockDim.x + threadIdx.x) * 4;
    if (i4 < n) {
        float4 v = *(const float4*)(src + i4);
        __half2 a = __floats2half2_rn(v.x, v.y);
        __half2 b = __floats2half2_rn(v.z, v.w);
        *(__half2*)(dst + i4)     = a;
        *(__half2*)(dst + i4 + 2) = b;
    }
}

// ---------------- CSR build ----------------
__global__ void deg_init_kernel(int* deg) {
    int i = blockIdx.x * blockDim.x + threadIdx.x;
    if (i < N_NODES) deg[i] = 1;   // self loop
}

__global__ void deg_count_kernel(const int* __restrict__ ei, int* deg) {
    int e = blockIdx.x * blockDim.x + threadIdx.x;
    if (e < N_EDGES) atomicAdd(&deg[ei[N_EDGES + e]], 1);
}

__global__ void scan1_kernel(const int* __restrict__ deg, int* offsets, int* partial) {
    __shared__ int buf[256];
    int t = threadIdx.x;
    int i = blockIdx.x * 256 + t;
    int v = (i < N_NODES) ? deg[i] : 0;
    buf[t] = v;
    __syncthreads();
    for (int off = 1; off < 256; off <<= 1) {
        int y = (t >= off) ? buf[t - off] : 0;
        __syncthreads();
        buf[t] += y;
        __syncthreads();
    }
    if (i < N_NODES) offsets[i] = buf[t] - v;       // local exclusive
    if (t == 255) partial[blockIdx.x] = buf[255];
}

__global__ void scan2_kernel(int* partial, int nb) {
    __shared__ int buf[256];
    int t = threadIdx.x;
    int v = (t < nb) ? partial[t] : 0;
    buf[t] = v;
    __syncthreads();
    for (int off = 1; off < 256; off <<= 1) {
        int y = (t >= off) ? buf[t - off] : 0;
        __syncthreads();
        buf[t] += y;
        __syncthreads();
    }
    if (t < nb) partial[t] = buf[t] - v;            // exclusive block prefix
}

__global__ void scan3_kernel(int* offsets, int* pos, const int* __restrict__ partial) {
    int i = blockIdx.x * 256 + threadIdx.x;
    if (i < N_NODES) {
        int o = offsets[i] + partial[i >> 8];
        offsets[i] = o;
        pos[i] = o;
    }
    if (i == 0) offsets[N_NODES] = N_EDGES + N_NODES;
}

__global__ void scatter_kernel(const int* __restrict__ ei, int* pos, int* csr_src) {
    int i = blockIdx.x * blockDim.x + threadIdx.x;
    if (i < N_EDGES) {
        int s = ei[i];
        int d = ei[N_EDGES + i];
        csr_src[atomicAdd(&pos[d], 1)] = s;
    } else if (i < N_EDGES + N_NODES) {
        int nn = i - N_EDGES;
        csr_src[atomicAdd(&pos[nn], 1)] = nn;
    }
}

// ------- MFMA GEMM: C[M,512] = A16[M,K] @ W16[K,512], fp16 in, fp32 acc, fp16 out ---
__global__ __launch_bounds__(256) void gemm_f16_kernel(const __half* __restrict__ A,
                                                       const __half* __restrict__ W16,
                                                       __half* __restrict__ C, int K) {
    __shared__ _Float16 As[64][136];   // [row][k]
    __shared__ _Float16 Bs[64][136];   // [col][k]
    int bm = blockIdx.x * 64;
    int bn = blockIdx.y * 64;
    int t = threadIdx.x;
    int lane = t & 63;
    int w = t >> 6;
    int wm = w >> 1, wn = w & 1;
    int lr = lane & 15;
    int lk = (lane >> 4) * 8;

    // stage full A tile [64][K]
    if (K == 64) {
        int row = t >> 3, k8 = (t & 7) * 8;
        #pragma unroll
        for (int rr = 0; rr < 64; rr += 32) {
            uint4 av = *(const uint4*)(A + (size_t)(bm + row + rr) * 64 + k8);
            *(uint4*)&As[row + rr][k8] = av;
        }
    } else {  // K == 128
        int row = t >> 4, k8 = (t & 15) * 8;
        #pragma unroll
        for (int rr = 0; rr < 64; rr += 16) {
            uint4 av = *(const uint4*)(A + (size_t)(bm + row + rr) * 128 + k8);
            *(uint4*)&As[row + rr][k8] = av;
        }
    }
    // stage B panel transposed: Bs[col][k]
    {
        int col = t & 63;
        int kb = (t >> 6) * 8;
        for (int k8 = kb; k8 < K; k8 += 32) {
            const __half* wp = W16 + (size_t)k8 * NCOLS + bn + col;
            uint u0 = (uint)__half_as_ushort(wp[0])         | ((uint)__half_as_ushort(wp[NCOLS])     << 16);
            uint u1 = (uint)__half_as_ushort(wp[2 * NCOLS]) | ((uint)__half_as_ushort(wp[3 * NCOLS]) << 16);
            uint u2 = (uint)__half_as_ushort(wp[4 * NCOLS]) | ((uint)__half_as_ushort(wp[5 * NCOLS]) << 16);
            uint u3 = (uint)__half_as_ushort(wp[6 * NCOLS]) | ((uint)__half_as_ushort(wp[7 * NCOLS]) << 16);
            uint4 uu = {u0, u1, u2, u3};
            *(uint4*)&Bs[col][k8] = uu;
        }
    }
    __syncthreads();

    f32x4 acc[2][2] = {};
    for (int k0 = 0; k0 < K; k0 += 32) {
        half8 af[2], bf[2];
        #pragma unroll
        for (int m = 0; m < 2; ++m) af[m] = *(const half8*)&As[wm * 32 + m * 16 + lr][k0 + lk];
        #pragma unroll
        for (int nn = 0; nn < 2; ++nn) bf[nn] = *(const half8*)&Bs[wn * 32 + nn * 16 + lr][k0 + lk];
        #pragma unroll
        for (int m = 0; m < 2; ++m)
            #pragma unroll
            for (int nn = 0; nn < 2; ++nn)
                acc[m][nn] = __builtin_amdgcn_mfma_f32_16x16x32_f16(af[m], bf[nn], acc[m][nn], 0, 0, 0);
    }

    int lg = lane >> 4;
    #pragma unroll
    for (int m = 0; m < 2; ++m) {
        #pragma unroll
        for (int nn = 0; nn < 2; ++nn) {
            int col = bn + wn * 32 + nn * 16 + lr;
            #pragma unroll
            for (int r = 0; r < 4; ++r) {
                int row = bm + wm * 32 + m * 16 + lg * 4 + r;
                C[(size_t)row * NCOLS + col] = __float2half(acc[m][nn][r]);
            }
        }
    }
}

// ---------------- attention scores per node: s = <xh[n,h,:], a[h,:]> ----------------
__global__ __launch_bounds__(256) void scores_kernel(const __half* __restrict__ xh,
                                                     const float* __restrict__ a_s,
                                                     const float* __restrict__ a_d,
                                                     float* __restrict__ s_src,
                                                     float* __restrict__ s_dst) {
    int node = blockIdx.x * 4 + (threadIdx.x >> 6);
    int lane = threadIdx.x & 63;
    if (node >= N_NODES) return;
    const __half* row = xh + (size_t)node * NCOLS;
    float ps[HEADS], pd[HEADS];
    #pragma unroll
    for (int h = 0; h < HEADS; ++h) {
        float v0 = __half2float(row[h * HID + lane]);
        float v1 = __half2float(row[h * HID + 64 + lane]);
        ps[h] = v0 * a_s[h * HID + lane] + v1 * a_s[h * HID + 64 + lane];
        pd[h] = v0 * a_d[h * HID + lane] + v1 * a_d[h * HID + 64 + lane];
    }
    #pragma unroll
    for (int off = 32; off > 0; off >>= 1) {
        #pragma unroll
        for (int h = 0; h < HEADS; ++h) {
            ps[h] += __shfl_down(ps[h], off);
            pd[h] += __shfl_down(pd[h], off);
        }
    }
    if (lane == 0) {
        #pragma unroll
        for (int h = 0; h < HEADS; ++h) {
            s_src[node * HEADS + h] = ps[h];
            s_dst[node * HEADS + h] = pd[h];
        }
    }
}

// ---- wave-per-node: softmax (in-register) + fp16 gather + head-mean + BN + ReLU ----
// 4 nodes per 256-block, one wave each. No __syncthreads anywhere.
// lane covers halves [lane*8, lane*8+8) of the 512-half xh row; head = lane>>4.
__device__ __forceinline__ void accum8(float* acc, uint4 u, float a) {
    __half2* hp = (__half2*)&u;
    #pragma unroll
    for (int q = 0; q < 4; ++q) {
        float2 f = __half22float2(hp[q]);
        acc[2 * q]     += a * f.x;
        acc[2 * q + 1] += a * f.y;
    }
}

__global__ __launch_bounds__(256) void aggregate_kernel(const __half* __restrict__ xh,
                                                        const float* __restrict__ s_src,
                                                        const float* __restrict__ s_dst,
                                                        const int* __restrict__ offsets,
                                                        const int* __restrict__ csr_src,
                                                        const float* __restrict__ bias,
                                                        const float* __restrict__ gamma,
                                                        const float* __restrict__ beta,
                                                        __half* __restrict__ h16out) {
    int wv = threadIdx.x >> 6;
    int lane = threadIdx.x & 63;
    int n = blockIdx.x * 4 + wv;
    if (n >= N_NODES) return;
    int start = offsets[n], end = offsets[n + 1];
    int deg = end - start;
    const float4 sd = *(const float4*)(s_dst + n * 4);
    int myh = lane >> 4;
    int coff = lane * 8;   // half offset into row

    __shared__ int   srcs[4][64];
    __shared__ float alpha[4][64][4];

    float acc[8] = {};

    if (deg <= 64) {
        bool act = lane < deg;
        int src = act ? csr_src[start + lane] : 0;
        float4 ss = *(const float4*)(s_src + src * 4);
        float e0 = act ? lrelu(ss.x + sd.x) : -1e30f;
        float e1 = act ? lrelu(ss.y + sd.y) : -1e30f;
        float e2 = act ? lrelu(ss.z + sd.z) : -1e30f;
        float e3 = act ? lrelu(ss.w + sd.w) : -1e30f;
        float m0 = e0, m1 = e1, m2 = e2, m3 = e3;
        #pragma unroll
        for (int o = 32; o > 0; o >>= 1) {
            m0 = fmaxf(m0, __shfl_xor(m0, o));
            m1 = fmaxf(m1, __shfl_xor(m1, o));
            m2 = fmaxf(m2, __shfl_xor(m2, o));
            m3 = fmaxf(m3, __shfl_xor(m3, o));
        }
        float p0 = __expf(e0 - m0), p1 = __expf(e1 - m1);
        float p2 = __expf(e2 - m2), p3 = __expf(e3 - m3);   // inactive: exp(-inf)=0
        float s0 = p0, s1 = p1, s2 = p2, s3 = p3;
        #pragma unroll
        for (int o = 32; o > 0; o >>= 1) {
            s0 += __shfl_xor(s0, o);
            s1 += __shfl_xor(s1, o);
            s2 += __shfl_xor(s2, o);
            s3 += __shfl_xor(s3, o);
        }
        f32x4 av = {p0 / s0, p1 / s1, p2 / s2, p3 / s3};
        srcs[wv][lane] = src;
        *(f32x4*)&alpha[wv][lane][0] = av;
        wave_lds_fence();

        int j = 0;
        for (; j + 2 <= deg; j += 2) {
            int sa = srcs[wv][j], sb = srcs[wv][j + 1];
            float aa = alpha[wv][j][myh], ab = alpha[wv][j + 1][myh];
            uint4 ua = *(const uint4*)(xh + (size_t)sa * NCOLS + coff);
            uint4 ub = *(const uint4*)(xh + (size_t)sb * NCOLS + coff);
            accum8(acc, ua, aa);
            accum8(acc, ub, ab);
        }
        if (j < deg) {
            int sa = srcs[wv][j];
            float aa = alpha[wv][j][myh];
            uint4 ua = *(const uint4*)(xh + (size_t)sa * NCOLS + coff);
            accum8(acc, ua, aa);
        }
    } else {
        // generic chunked path (deg > 64): 3 passes over edges
        float m0 = -1e30f, m1 = -1e30f, m2 = -1e30f, m3 = -1e30f;
        for (int j0 = 0; j0 < deg; j0 += 64) {
            int j = j0 + lane;
            bool act = j < deg;
            int src = act ? csr_src[start + j] : 0;
            float4 ss = *(const float4*)(s_src + src * 4);
            m0 = fmaxf(m0, act ? lrelu(ss.x + sd.x) : -1e30f);
            m1 = fmaxf(m1, act ? lrelu(ss.y + sd.y) : -1e30f);
            m2 = fmaxf(m2, act ? lrelu(ss.z + sd.z) : -1e30f);
            m3 = fmaxf(m3, act ? lrelu(ss.w + sd.w) : -1e30f);
        }
        #pragma unroll
        for (int o = 32; o > 0; o >>= 1) {
            m0 = fmaxf(m0, __shfl_xor(m0, o));
            m1 = fmaxf(m1, __shfl_xor(m1, o));
            m2 = fmaxf(m2, __shfl_xor(m2, o));
            m3 = fmaxf(m3, __shfl_xor(m3, o));
        }
        float s0 = 0.f, s1 = 0.f, s2 = 0.f, s3 = 0.f;
        for (int j0 = 0; j0 < deg; j0 += 64) {
            int j = j0 + lane;
            bool act = j < deg;
            int src = act ? csr_src[start + j] : 0;
            float4 ss = *(const float4*)(s_src + src * 4);
            s0 += act ? __expf(lrelu(ss.x + sd.x) - m0) : 0.f;
            s1 += act ? __expf(lrelu(ss.y + sd.y) - m1) : 0.f;
            s2 += act ? __expf(lrelu(ss.z + sd.z) - m2) : 0.f;
            s3 += act ? __expf(lrelu(ss.w + sd.w) - m3) : 0.f;
        }
        #pragma unroll
        for (int o = 32; o > 0; o >>= 1) {
            s0 += __shfl_xor(s0, o);
            s1 += __shfl_xor(s1, o);
            s2 += __shfl_xor(s2, o);
            s3 += __shfl_xor(s3, o);
        }
        float i0 = 1.f / s0, i1 = 1.f / s1, i2 = 1.f / s2, i3 = 1.f / s3;
        for (int j0 = 0; j0 < deg; j0 += 64) {
            int j = j0 + lane;
            bool act = j < deg;
            int src = act ? csr_src[start + j] : 0;
            float4 ss = *(const float4*)(s_src + src * 4);
            f32x4 av;
            av[0] = act ? __expf(lrelu(ss.x + sd.x) - m0) * i0 : 0.f;
            av[1] = act ? __expf(lrelu(ss.y + sd.y) - m1) * i1 : 0.f;
            av[2] = act ? __expf(lrelu(ss.z + sd.z) - m2) * i2 : 0.f;
            av[3] = act ? __expf(lrelu(ss.w + sd.w) - m3) * i3 : 0.f;
            srcs[wv][lane] = src;
            *(f32x4*)&alpha[wv][lane][0] = av;
            wave_lds_fence();
            int cend = min(64, deg - j0);
            for (int jj = 0; jj < cend; ++jj) {
                int sa = srcs[wv][jj];
                float aa = alpha[wv][jj][myh];
                uint4 ua = *(const uint4*)(xh + (size_t)sa * NCOLS + coff);
                accum8(acc, ua, aa);
            }
            wave_lds_fence();   // reads done before next chunk overwrites
        }
    }

    // cross-head mean: lanes {l, l+16, l+32, l+48} hold same channels for heads 0..3
    #pragma unroll
    for (int r = 0; r < 8; ++r) {
        acc[r] += __shfl_xor(acc[r], 16);
        acc[r] += __shfl_xor(acc[r], 32);
    }
    if (lane < 16) {
        int cb = lane * 8;
        ushort us[8];
        #pragma unroll
        for (int r = 0; r < 8; ++r) {
            int c = cb + r;
            float o = acc[r] * 0.25f + bias[c];
            o = o * (gamma[c] * rsqrtf(1.f + 1e-5f)) + beta[c];
            o = fmaxf(o, 0.f);
            us[r] = __half_as_ushort(__float2half(o));
        }
        uint4 pack;
        pack.x = (uint)us[0] | ((uint)us[1] << 16);
        pack.y = (uint)us[2] | ((uint)us[3] << 16);
        pack.z = (uint)us[4] | ((uint)us[5] << 16);
        pack.w = (uint)us[6] | ((uint)us[7] << 16);
        *(uint4*)(h16out + (size_t)n * HID + cb) = pack;
    }
}

// ---------------- pooling (batch sorted -> run-length partial sums) ----------------
__global__ __launch_bounds__(128) void pool_kernel(const __half* __restrict__ h,
                                                   const int* __restrict__ batch,
                                                   float* pooled, float* counts) {
    int t = threadIdx.x;
    int n0 = blockIdx.x * 256;
    int n1 = min(n0 + 256, N_NODES);
    if (n0 >= N_NODES) return;
    int cg = batch[n0];
    float acc = 0.f, cnt = 0.f;
    for (int n = n0; n < n1; ++n) {
        int g = batch[n];
        if (g != cg) {
            atomicAdd(&pooled[cg * HID + t], acc);
            if (t == 0) atomicAdd(&counts[cg], cnt);
            acc = 0.f; cnt = 0.f; cg = g;
        }
        acc += __half2float(h[(size_t)n * HID + t]);
        cnt += 1.f;
    }
    atomicAdd(&pooled[cg * HID + t], acc);
    if (t == 0) atomicAdd(&counts[cg], cnt);
}

// ---------------- head: mean-divide + fc1 + relu + fc2 ----------------
__global__ __launch_bounds__(128) void head_kernel(const float* __restrict__ pooled,
                                                   const float* __restrict__ counts,
                                                   const float* __restrict__ fc1_w,
                                                   const float* __restrict__ fc1_b,
                                                   const float* __restrict__ fc2_w,
                                                   const float* __restrict__ fc2_b,
                                                   float* __restrict__ out) {
    int gI = blockIdx.x;
    int t = threadIdx.x;
    __shared__ float p[HID], hb[HID];
    p[t] = pooled[gI * HID + t] / fmaxf(counts[gI], 1.f);
    __syncthreads();
    float a = fc1_b[t];
    #pragma unroll 4
    for (int k = 0; k < HID; ++k) a += p[k] * fc1_w[k * HID + t];
    hb[t] = fmaxf(a, 0.f);
    __syncthreads();
    if (t < OUTDIM) {
        float o = fc2_b[t];
        #pragma unroll 4
        for (int k = 0; k < HID; ++k) o += hb[k] * fc2_w[k * OUTDIM + t];
        out[gI * OUTDIM + t] = o;
    }
}

extern "C" void kernel_launch(void* const* d_in, const int* in_sizes, int n_in,
                              void* d_out, int out_size, void* d_ws, size_t ws_size,
                              hipStream_t stream) {
    const float* x     = (const float*)d_in[0];
    const int*   ei    = (const int*)d_in[1];
    const int*   batch = (const int*)d_in[2];
    const float* W[3]  = {(const float*)d_in[3],  (const float*)d_in[9],  (const float*)d_in[15]};
    const float* As[3] = {(const float*)d_in[4],  (const float*)d_in[10], (const float*)d_in[16]};
    const float* Ad[3] = {(const float*)d_in[5],  (const float*)d_in[11], (const float*)d_in[17]};
    const float* Bb[3] = {(const float*)d_in[6],  (const float*)d_in[12], (const float*)d_in[18]};
    const float* Gg[3] = {(const float*)d_in[7],  (const float*)d_in[13], (const float*)d_in[19]};
    const float* Be[3] = {(const float*)d_in[8],  (const float*)d_in[14], (const float*)d_in[20]};
    const float* fc1_w = (const float*)d_in[21];
    const float* fc1_b = (const float*)d_in[22];
    const float* fc2_w = (const float*)d_in[23];
    const float* fc2_b = (const float*)d_in[24];

    char* ws = (char*)d_ws;
    size_t off = 0;
    auto alloc = [&](size_t bytes) {
        void* p = ws + off;
        off = (off + bytes + 255) & ~(size_t)255;
        return p;
    };
    __half* xh     = (__half*)alloc((size_t)N_NODES * NCOLS * 2);
    __half* x16    = (__half*)alloc((size_t)N_NODES * FIN * 2);
    __half* h16    = (__half*)alloc((size_t)N_NODES * HID * 2);
    __half* W16[3];
    W16[0] = (__half*)alloc((size_t)FIN * NCOLS * 2);
    W16[1] = (__half*)alloc((size_t)HID * NCOLS * 2);
    W16[2] = (__half*)alloc((size_t)HID * NCOLS * 2);
    float* ssrc    = (float*)alloc((size_t)N_NODES * HEADS * 4);
    float* sdst    = (float*)alloc((size_t)N_NODES * HEADS * 4);
    int*   deg     = (int*)alloc((size_t)N_NODES * 4);
    int*   offsets = (int*)alloc((size_t)(N_NODES + 1) * 4);
    int*   pos     = (int*)alloc((size_t)N_NODES * 4);
    int*   partial = (int*)alloc((size_t)256 * 4);
    int*   csr     = (int*)alloc((size_t)(N_EDGES + N_NODES) * 4);
    float* pooled  = (float*)alloc((size_t)NGROUPS * HID * 4);
    float* counts  = (float*)alloc((size_t)NGROUPS * 4);

    // fp16 conversions
    f32to16_kernel<<<(N_NODES * FIN / 4 + 255) / 256, 256, 0, stream>>>(x, x16, N_NODES * FIN);
    f32to16_kernel<<<(FIN * NCOLS / 4 + 255) / 256, 256, 0, stream>>>(W[0], W16[0], FIN * NCOLS);
    f32to16_kernel<<<(HID * NCOLS / 4 + 255) / 256, 256, 0, stream>>>(W[1], W16[1], HID * NCOLS);
    f32to16_kernel<<<(HID * NCOLS / 4 + 255) / 256, 256, 0, stream>>>(W[2], W16[2], HID * NCOLS);

    // CSR by dst (with self loops)
    const int NB = (N_NODES + 255) / 256;   // 157
    deg_init_kernel<<<NB, 256, 0, stream>>>(deg);
    deg_count_kernel<<<(N_EDGES + 255) / 256, 256, 0, stream>>>(ei, deg);
    scan1_kernel<<<NB, 256, 0, stream>>>(deg, offsets, partial);
    scan2_kernel<<<1, 256, 0, stream>>>(partial, NB);
    scan3_kernel<<<NB, 256, 0, stream>>>(offsets, pos, partial);
    scatter_kernel<<<(N_EDGES + N_NODES + 255) / 256, 256, 0, stream>>>(ei, pos, csr);

    // 3 GAT layers
    const __half* Ain = x16;
    for (int l = 0; l < 3; ++l) {
        int K = (l == 0) ? FIN : HID;
        gemm_f16_kernel<<<dim3(N_NODES / 64, NCOLS / 64), 256, 0, stream>>>(Ain, W16[l], xh, K);
        scores_kernel<<<(N_NODES + 3) / 4, 256, 0, stream>>>(xh, As[l], Ad[l], ssrc, sdst);
        aggregate_kernel<<<(N_NODES + 3) / 4, 256, 0, stream>>>(xh, ssrc, sdst, offsets, csr,
                                                                Bb[l], Gg[l], Be[l], h16);
        Ain = h16;
    }

    // global mean pool + MLP head
    hipMemsetAsync(pooled, 0, (size_t)NGROUPS * HID * 4, stream);
    hipMemsetAsync(counts, 0, (size_t)NGROUPS * 4, stream);
    pool_kernel<<<(N_NODES + 255) / 256, 128, 0, stream>>>(h16, batch, pooled, counts);
    head_kernel<<<NGROUPS, 128, 0, stream>>>(pooled, counts, fc1_w, fc1_b, fc2_w, fc2_b,
                                             (float*)d_out);
}

// Round 6
// 571.510 us; speedup vs baseline: 1.9622x; 1.0358x over previous
//
#include <hip/hip_runtime.h>
#include <hip/hip_fp16.h>
#include <math.h>

#define N_NODES 40000
#define N_EDGES 640000
#define FIN 64
#define HID 128
#define OUTDIM 64
#define HEADS 4
#define NGROUPS 64
#define NCOLS 512   // HEADS*HID

typedef _Float16 half8 __attribute__((ext_vector_type(8)));
typedef float f32x4 __attribute__((ext_vector_type(4)));

__device__ __forceinline__ float lrelu(float x) { return x > 0.f ? x : 0.2f * x; }

__device__ __forceinline__ void wave_lds_fence() {
    asm volatile("s_waitcnt lgkmcnt(0)" ::: "memory");
}

// ---------------- fp32 -> fp16 convert ----------------
__global__ void f32to16_kernel(const float* __restrict__ src, __half* __restrict__ dst, int n) {
    int i4 = (blockIdx.x * blockDim.x + threadIdx.x) * 4;
    if (i4 < n) {
        float4 v = *(const float4*)(src + i4);
        __half2 a = __floats2half2_rn(v.x, v.y);
        __half2 b = __floats2half2_rn(v.z, v.w);
        *(__half2*)(dst + i4)     = a;
        *(__half2*)(dst + i4 + 2) = b;
    }
}

// ---------------- CSR build ----------------
__global__ void deg_init_kernel(int* deg) {
    int i = blockIdx.x * blockDim.x + threadIdx.x;
    if (i < N_NODES) deg[i] = 1;   // self loop
}

__global__ void deg_count_kernel(const int* __restrict__ ei, int* deg) {
    int e = blockIdx.x * blockDim.x + threadIdx.x;
    if (e < N_EDGES) atomicAdd(&deg[ei[N_EDGES + e]], 1);
}

__global__ void scan1_kernel(const int* __restrict__ deg, int* offsets, int* partial) {
    __shared__ int buf[256];
    int t = threadIdx.x;
    int i = blockIdx.x * 256 + t;
    int v = (i < N_NODES) ? deg[i] : 0;
    buf[t] = v;
    __syncthreads();
    for (int off = 1; off < 256; off <<= 1) {
        int y = (t >= off) ? buf[t - off] : 0;
        __syncthreads();
        buf[t] += y;
        __syncthreads();
    }
    if (i < N_NODES) offsets[i] = buf[t] - v;       // local exclusive
    if (t == 255) partial[blockIdx.x] = buf[255];
}

__global__ void scan2_kernel(int* partial, int nb) {
    __shared__ int buf[256];
    int t = threadIdx.x;
    int v = (t < nb) ? partial[t] : 0;
    buf[t] = v;
    __syncthreads();
    for (int off = 1; off < 256; off <<= 1) {
        int y = (t >= off) ? buf[t - off] : 0;
        __syncthreads();
        buf[t] += y;
        __syncthreads();
    }
    if (t < nb) partial[t] = buf[t] - v;            // exclusive block prefix
}

__global__ void scan3_kernel(int* offsets, int* pos, const int* __restrict__ partial) {
    int i = blockIdx.x * 256 + threadIdx.x;
    if (i < N_NODES) {
        int o = offsets[i] + partial[i >> 8];
        offsets[i] = o;
        pos[i] = o;
    }
    if (i == 0) offsets[N_NODES] = N_EDGES + N_NODES;
}

__global__ void scatter_kernel(const int* __restrict__ ei, int* pos, int* csr_src) {
    int i = blockIdx.x * blockDim.x + threadIdx.x;
    if (i < N_EDGES) {
        int s = ei[i];
        int d = ei[N_EDGES + i];
        csr_src[atomicAdd(&pos[d], 1)] = s;
    } else if (i < N_EDGES + N_NODES) {
        int nn = i - N_EDGES;
        csr_src[atomicAdd(&pos[nn], 1)] = nn;
    }
}

// ------- MFMA GEMM: C[M,512] = A16[M,K] @ W16[K,512], fp16 in, fp32 acc, fp16 out ---
__global__ __launch_bounds__(256) void gemm_f16_kernel(const __half* __restrict__ A,
                                                       const __half* __restrict__ W16,
                                                       __half* __restrict__ C, int K) {
    __shared__ _Float16 As[64][136];   // [row][k]
    __shared__ _Float16 Bs[64][136];   // [col][k]
    int bm = blockIdx.x * 64;
    int bn = blockIdx.y * 64;
    int t = threadIdx.x;
    int lane = t & 63;
    int w = t >> 6;
    int wm = w >> 1, wn = w & 1;
    int lr = lane & 15;
    int lk = (lane >> 4) * 8;

    // stage full A tile [64][K]
    if (K == 64) {
        int row = t >> 3, k8 = (t & 7) * 8;
        #pragma unroll
        for (int rr = 0; rr < 64; rr += 32) {
            uint4 av = *(const uint4*)(A + (size_t)(bm + row + rr) * 64 + k8);
            *(uint4*)&As[row + rr][k8] = av;
        }
    } else {  // K == 128
        int row = t >> 4, k8 = (t & 15) * 8;
        #pragma unroll
        for (int rr = 0; rr < 64; rr += 16) {
            uint4 av = *(const uint4*)(A + (size_t)(bm + row + rr) * 128 + k8);
            *(uint4*)&As[row + rr][k8] = av;
        }
    }
    // stage B panel transposed: Bs[col][k]
    {
        int col = t & 63;
        int kb = (t >> 6) * 8;
        for (int k8 = kb; k8 < K; k8 += 32) {
            const __half* wp = W16 + (size_t)k8 * NCOLS + bn + col;
            uint u0 = (uint)__half_as_ushort(wp[0])         | ((uint)__half_as_ushort(wp[NCOLS])     << 16);
            uint u1 = (uint)__half_as_ushort(wp[2 * NCOLS]) | ((uint)__half_as_ushort(wp[3 * NCOLS]) << 16);
            uint u2 = (uint)__half_as_ushort(wp[4 * NCOLS]) | ((uint)__half_as_ushort(wp[5 * NCOLS]) << 16);
            uint u3 = (uint)__half_as_ushort(wp[6 * NCOLS]) | ((uint)__half_as_ushort(wp[7 * NCOLS]) << 16);
            uint4 uu = {u0, u1, u2, u3};
            *(uint4*)&Bs[col][k8] = uu;
        }
    }
    __syncthreads();

    f32x4 acc[2][2] = {};
    for (int k0 = 0; k0 < K; k0 += 32) {
        half8 af[2], bf[2];
        #pragma unroll
        for (int m = 0; m < 2; ++m) af[m] = *(const half8*)&As[wm * 32 + m * 16 + lr][k0 + lk];
        #pragma unroll
        for (int nn = 0; nn < 2; ++nn) bf[nn] = *(const half8*)&Bs[wn * 32 + nn * 16 + lr][k0 + lk];
        #pragma unroll
        for (int m = 0; m < 2; ++m)
            #pragma unroll
            for (int nn = 0; nn < 2; ++nn)
                acc[m][nn] = __builtin_amdgcn_mfma_f32_16x16x32_f16(af[m], bf[nn], acc[m][nn], 0, 0, 0);
    }

    int lg = lane >> 4;
    #pragma unroll
    for (int m = 0; m < 2; ++m) {
        #pragma unroll
        for (int nn = 0; nn < 2; ++nn) {
            int col = bn + wn * 32 + nn * 16 + lr;
            #pragma unroll
            for (int r = 0; r < 4; ++r) {
                int row = bm + wm * 32 + m * 16 + lg * 4 + r;
                C[(size_t)row * NCOLS + col] = __float2half(acc[m][nn][r]);
            }
        }
    }
}

// ------- scores via linearity: v[k][j] = sum_c W[k, h*128+c]*a_{s|d}[h,c]  (j=sd*4+h)
__global__ void prep_v_kernel(const float* __restrict__ W,
                              const float* __restrict__ a_s,
                              const float* __restrict__ a_d,
                              float* __restrict__ v, int K) {
    int j = blockIdx.x * blockDim.x + threadIdx.x;
    if (j >= K * 8) return;
    int k = j >> 3, sd = (j >> 2) & 1, h = j & 3;
    const float* av = sd ? a_d : a_s;
    float acc = 0.f;
    for (int c = 0; c < HID; ++c)
        acc += W[(size_t)k * NCOLS + h * HID + c] * av[h * HID + c];
    v[k * 8 + sd * 4 + h] = acc;
}

// ------- s[n, j] = sum_k x16[n,k] * v[k,j]   (j: 0-3 src heads, 4-7 dst heads)
__global__ __launch_bounds__(256) void scores2_kernel(const __half* __restrict__ x,
                                                      const float* __restrict__ v,
                                                      float* __restrict__ ssrc,
                                                      float* __restrict__ sdst, int K) {
    int node = blockIdx.x * 32 + (threadIdx.x >> 3);
    int j = threadIdx.x & 7;
    if (node >= N_NODES) return;
    const __half* xr = x + (size_t)node * K;
    float acc = 0.f;
    for (int k0 = 0; k0 < K; k0 += 8) {
        uint4 u = *(const uint4*)(xr + k0);
        __half2* hp = (__half2*)&u;
        #pragma unroll
        for (int q = 0; q < 4; ++q) {
            float2 f = __half22float2(hp[q]);
            acc += f.x * v[(k0 + 2 * q) * 8 + j] + f.y * v[(k0 + 2 * q + 1) * 8 + j];
        }
    }
    if (j < 4) ssrc[node * 4 + j] = acc;
    else       sdst[node * 4 + (j - 4)] = acc;
}

// ---- wave-per-node: softmax (in-register) + fp16 gather + head-mean + BN + ReLU ----
__device__ __forceinline__ void accum8(float* acc, uint4 u, float a) {
    __half2* hp = (__half2*)&u;
    #pragma unroll
    for (int q = 0; q < 4; ++q) {
        float2 f = __half22float2(hp[q]);
        acc[2 * q]     += a * f.x;
        acc[2 * q + 1] += a * f.y;
    }
}

__global__ __launch_bounds__(256) void aggregate_kernel(const __half* __restrict__ xh,
                                                        const float* __restrict__ s_src,
                                                        const float* __restrict__ s_dst,
                                                        const int* __restrict__ offsets,
                                                        const int* __restrict__ csr_src,
                                                        const float* __restrict__ bias,
                                                        const float* __restrict__ gamma,
                                                        const float* __restrict__ beta,
                                                        __half* __restrict__ h16out) {
    int wv = threadIdx.x >> 6;
    int lane = threadIdx.x & 63;
    int n = blockIdx.x * 4 + wv;
    if (n >= N_NODES) return;
    int start = offsets[n], end = offsets[n + 1];
    int deg = end - start;
    const float4 sd = *(const float4*)(s_dst + n * 4);
    int myh = lane >> 4;

    __shared__ int   srcs[4][64];
    __shared__ float alpha[4][64][4];

    float acc[8] = {};
    const char* xb = (const char*)xh + lane * 16;   // lane covers halves [lane*8, lane*8+8)

    if (deg <= 64) {
        bool act = lane < deg;
        int src = act ? csr_src[start + lane] : 0;
        float4 ss = *(const float4*)(s_src + src * 4);
        float e0 = act ? lrelu(ss.x + sd.x) : -1e30f;
        float e1 = act ? lrelu(ss.y + sd.y) : -1e30f;
        float e2 = act ? lrelu(ss.z + sd.z) : -1e30f;
        float e3 = act ? lrelu(ss.w + sd.w) : -1e30f;
        float m0 = e0, m1 = e1, m2 = e2, m3 = e3;
        #pragma unroll
        for (int o = 32; o > 0; o >>= 1) {
            m0 = fmaxf(m0, __shfl_xor(m0, o));
            m1 = fmaxf(m1, __shfl_xor(m1, o));
            m2 = fmaxf(m2, __shfl_xor(m2, o));
            m3 = fmaxf(m3, __shfl_xor(m3, o));
        }
        float p0 = __expf(e0 - m0), p1 = __expf(e1 - m1);
        float p2 = __expf(e2 - m2), p3 = __expf(e3 - m3);   // inactive: exp(-inf)=0
        float s0 = p0, s1 = p1, s2 = p2, s3 = p3;
        #pragma unroll
        for (int o = 32; o > 0; o >>= 1) {
            s0 += __shfl_xor(s0, o);
            s1 += __shfl_xor(s1, o);
            s2 += __shfl_xor(s2, o);
            s3 += __shfl_xor(s3, o);
        }
        f32x4 av = {p0 / s0, p1 / s1, p2 / s2, p3 / s3};
        srcs[wv][lane] = src;
        *(f32x4*)&alpha[wv][lane][0] = av;
        wave_lds_fence();

        int j = 0;
        for (; j + 4 <= deg; j += 4) {
            uint o0 = (uint)srcs[wv][j]     << 10;
            uint o1 = (uint)srcs[wv][j + 1] << 10;
            uint o2 = (uint)srcs[wv][j + 2] << 10;
            uint o3 = (uint)srcs[wv][j + 3] << 10;
            float a0 = alpha[wv][j][myh];
            float a1 = alpha[wv][j + 1][myh];
            float a2 = alpha[wv][j + 2][myh];
            float a3 = alpha[wv][j + 3][myh];
            uint4 u0 = *(const uint4*)(xb + o0);
            uint4 u1 = *(const uint4*)(xb + o1);
            uint4 u2 = *(const uint4*)(xb + o2);
            uint4 u3 = *(const uint4*)(xb + o3);
            accum8(acc, u0, a0);
            accum8(acc, u1, a1);
            accum8(acc, u2, a2);
            accum8(acc, u3, a3);
        }
        for (; j < deg; ++j) {
            uint o0 = (uint)srcs[wv][j] << 10;
            float a0 = alpha[wv][j][myh];
            uint4 u0 = *(const uint4*)(xb + o0);
            accum8(acc, u0, a0);
        }
    } else {
        // generic chunked path (deg > 64): 3 passes over edges
        float m0 = -1e30f, m1 = -1e30f, m2 = -1e30f, m3 = -1e30f;
        for (int j0 = 0; j0 < deg; j0 += 64) {
            int j = j0 + lane;
            bool act = j < deg;
            int src = act ? csr_src[start + j] : 0;
            float4 ss = *(const float4*)(s_src + src * 4);
            m0 = fmaxf(m0, act ? lrelu(ss.x + sd.x) : -1e30f);
            m1 = fmaxf(m1, act ? lrelu(ss.y + sd.y) : -1e30f);
            m2 = fmaxf(m2, act ? lrelu(ss.z + sd.z) : -1e30f);
            m3 = fmaxf(m3, act ? lrelu(ss.w + sd.w) : -1e30f);
        }
        #pragma unroll
        for (int o = 32; o > 0; o >>= 1) {
            m0 = fmaxf(m0, __shfl_xor(m0, o));
            m1 = fmaxf(m1, __shfl_xor(m1, o));
            m2 = fmaxf(m2, __shfl_xor(m2, o));
            m3 = fmaxf(m3, __shfl_xor(m3, o));
        }
        float s0 = 0.f, s1 = 0.f, s2 = 0.f, s3 = 0.f;
        for (int j0 = 0; j0 < deg; j0 += 64) {
            int j = j0 + lane;
            bool act = j < deg;
            int src = act ? csr_src[start + j] : 0;
            float4 ss = *(const float4*)(s_src + src * 4);
            s0 += act ? __expf(lrelu(ss.x + sd.x) - m0) : 0.f;
            s1 += act ? __expf(lrelu(ss.y + sd.y) - m1) : 0.f;
            s2 += act ? __expf(lrelu(ss.z + sd.z) - m2) : 0.f;
            s3 += act ? __expf(lrelu(ss.w + sd.w) - m3) : 0.f;
        }
        #pragma unroll
        for (int o = 32; o > 0; o >>= 1) {
            s0 += __shfl_xor(s0, o);
            s1 += __shfl_xor(s1, o);
            s2 += __shfl_xor(s2, o);
            s3 += __shfl_xor(s3, o);
        }
        float i0 = 1.f / s0, i1 = 1.f / s1, i2 = 1.f / s2, i3 = 1.f / s3;
        for (int j0 = 0; j0 < deg; j0 += 64) {
            int j = j0 + lane;
            bool act = j < deg;
            int src = act ? csr_src[start + j] : 0;
            float4 ss = *(const float4*)(s_src + src * 4);
            f32x4 av;
            av[0] = act ? __expf(lrelu(ss.x + sd.x) - m0) * i0 : 0.f;
            av[1] = act ? __expf(lrelu(ss.y + sd.y) - m1) * i1 : 0.f;
            av[2] = act ? __expf(lrelu(ss.z + sd.z) - m2) * i2 : 0.f;
            av[3] = act ? __expf(lrelu(ss.w + sd.w) - m3) * i3 : 0.f;
            srcs[wv][lane] = src;
            *(f32x4*)&alpha[wv][lane][0] = av;
            wave_lds_fence();
            int cend = min(64, deg - j0);
            for (int jj = 0; jj < cend; ++jj) {
                uint o0 = (uint)srcs[wv][jj] << 10;
                float aa = alpha[wv][jj][myh];
                uint4 ua = *(const uint4*)(xb + o0);
                accum8(acc, ua, aa);
            }
            wave_lds_fence();   // reads done before next chunk overwrites
        }
    }

    // cross-head mean: lanes {l, l+16, l+32, l+48} hold same channels for heads 0..3
    #pragma unroll
    for (int r = 0; r < 8; ++r) {
        acc[r] += __shfl_xor(acc[r], 16);
        acc[r] += __shfl_xor(acc[r], 32);
    }
    if (lane < 16) {
        int cb = lane * 8;
        ushort us[8];
        #pragma unroll
        for (int r = 0; r < 8; ++r) {
            int c = cb + r;
            float o = acc[r] * 0.25f + bias[c];
            o = o * (gamma[c] * rsqrtf(1.f + 1e-5f)) + beta[c];
            o = fmaxf(o, 0.f);
            us[r] = __half_as_ushort(__float2half(o));
        }
        uint4 pack;
        pack.x = (uint)us[0] | ((uint)us[1] << 16);
        pack.y = (uint)us[2] | ((uint)us[3] << 16);
        pack.z = (uint)us[4] | ((uint)us[5] << 16);
        pack.w = (uint)us[6] | ((uint)us[7] << 16);
        *(uint4*)(h16out + (size_t)n * HID + cb) = pack;
    }
}

// ---------------- pooling (batch sorted -> run-length partial sums) ----------------
__global__ __launch_bounds__(128) void pool_kernel(const __half* __restrict__ h,
                                                   const int* __restrict__ batch,
                                                   float* pooled, float* counts) {
    int t = threadIdx.x;
    int n0 = blockIdx.x * 256;
    int n1 = min(n0 + 256, N_NODES);
    if (n0 >= N_NODES) return;
    int cg = batch[n0];
    float acc = 0.f, cnt = 0.f;
    for (int n = n0; n < n1; ++n) {
        int g = batch[n];
        if (g != cg) {
            atomicAdd(&pooled[cg * HID + t], acc);
            if (t == 0) atomicAdd(&counts[cg], cnt);
            acc = 0.f; cnt = 0.f; cg = g;
        }
        acc += __half2float(h[(size_t)n * HID + t]);
        cnt += 1.f;
    }
    atomicAdd(&pooled[cg * HID + t], acc);
    if (t == 0) atomicAdd(&counts[cg], cnt);
}

// ---------------- head: mean-divide + fc1 + relu + fc2 ----------------
__global__ __launch_bounds__(128) void head_kernel(const float* __restrict__ pooled,
                                                   const float* __restrict__ counts,
                                                   const float* __restrict__ fc1_w,
                                                   const float* __restrict__ fc1_b,
                                                   const float* __restrict__ fc2_w,
                                                   const float* __restrict__ fc2_b,
                                                   float* __restrict__ out) {
    int gI = blockIdx.x;
    int t = threadIdx.x;
    __shared__ float p[HID], hb[HID];
    p[t] = pooled[gI * HID + t] / fmaxf(counts[gI], 1.f);
    __syncthreads();
    float a = fc1_b[t];
    #pragma unroll 4
    for (int k = 0; k < HID; ++k) a += p[k] * fc1_w[k * HID + t];
    hb[t] = fmaxf(a, 0.f);
    __syncthreads();
    if (t < OUTDIM) {
        float o = fc2_b[t];
        #pragma unroll 4
        for (int k = 0; k < HID; ++k) o += hb[k] * fc2_w[k * OUTDIM + t];
        out[gI * OUTDIM + t] = o;
    }
}

extern "C" void kernel_launch(void* const* d_in, const int* in_sizes, int n_in,
                              void* d_out, int out_size, void* d_ws, size_t ws_size,
                              hipStream_t stream) {
    const float* x     = (const float*)d_in[0];
    const int*   ei    = (const int*)d_in[1];
    const int*   batch = (const int*)d_in[2];
    const float* W[3]  = {(const float*)d_in[3],  (const float*)d_in[9],  (const float*)d_in[15]};
    const float* As[3] = {(const float*)d_in[4],  (const float*)d_in[10], (const float*)d_in[16]};
    const float* Ad[3] = {(const float*)d_in[5],  (const float*)d_in[11], (const float*)d_in[17]};
    const float* Bb[3] = {(const float*)d_in[6],  (const float*)d_in[12], (const float*)d_in[18]};
    const float* Gg[3] = {(const float*)d_in[7],  (const float*)d_in[13], (const float*)d_in[19]};
    const float* Be[3] = {(const float*)d_in[8],  (const float*)d_in[14], (const float*)d_in[20]};
    const float* fc1_w = (const float*)d_in[21];
    const float* fc1_b = (const float*)d_in[22];
    const float* fc2_w = (const float*)d_in[23];
    const float* fc2_b = (const float*)d_in[24];

    char* ws = (char*)d_ws;
    size_t off = 0;
    auto alloc = [&](size_t bytes) {
        void* p = ws + off;
        off = (off + bytes + 255) & ~(size_t)255;
        return p;
    };
    __half* xh     = (__half*)alloc((size_t)N_NODES * NCOLS * 2);
    __half* x16    = (__half*)alloc((size_t)N_NODES * FIN * 2);
    __half* h16    = (__half*)alloc((size_t)N_NODES * HID * 2);
    __half* W16[3];
    W16[0] = (__half*)alloc((size_t)FIN * NCOLS * 2);
    W16[1] = (__half*)alloc((size_t)HID * NCOLS * 2);
    W16[2] = (__half*)alloc((size_t)HID * NCOLS * 2);
    float* vtab[3];
    vtab[0] = (float*)alloc((size_t)FIN * 8 * 4);
    vtab[1] = (float*)alloc((size_t)HID * 8 * 4);
    vtab[2] = (float*)alloc((size_t)HID * 8 * 4);
    float* ssrc    = (float*)alloc((size_t)N_NODES * HEADS * 4);
    float* sdst    = (float*)alloc((size_t)N_NODES * HEADS * 4);
    int*   deg     = (int*)alloc((size_t)N_NODES * 4);
    int*   offsets = (int*)alloc((size_t)(N_NODES + 1) * 4);
    int*   pos     = (int*)alloc((size_t)N_NODES * 4);
    int*   partial = (int*)alloc((size_t)256 * 4);
    int*   csr     = (int*)alloc((size_t)(N_EDGES + N_NODES) * 4);
    float* pooled  = (float*)alloc((size_t)NGROUPS * HID * 4);
    float* counts  = (float*)alloc((size_t)NGROUPS * 4);

    // fp16 conversions + per-layer score vectors
    f32to16_kernel<<<(N_NODES * FIN / 4 + 255) / 256, 256, 0, stream>>>(x, x16, N_NODES * FIN);
    f32to16_kernel<<<(FIN * NCOLS / 4 + 255) / 256, 256, 0, stream>>>(W[0], W16[0], FIN * NCOLS);
    f32to16_kernel<<<(HID * NCOLS / 4 + 255) / 256, 256, 0, stream>>>(W[1], W16[1], HID * NCOLS);
    f32to16_kernel<<<(HID * NCOLS / 4 + 255) / 256, 256, 0, stream>>>(W[2], W16[2], HID * NCOLS);
    prep_v_kernel<<<(FIN * 8 + 255) / 256, 256, 0, stream>>>(W[0], As[0], Ad[0], vtab[0], FIN);
    prep_v_kernel<<<(HID * 8 + 255) / 256, 256, 0, stream>>>(W[1], As[1], Ad[1], vtab[1], HID);
    prep_v_kernel<<<(HID * 8 + 255) / 256, 256, 0, stream>>>(W[2], As[2], Ad[2], vtab[2], HID);

    // CSR by dst (with self loops)
    const int NB = (N_NODES + 255) / 256;   // 157
    deg_init_kernel<<<NB, 256, 0, stream>>>(deg);
    deg_count_kernel<<<(N_EDGES + 255) / 256, 256, 0, stream>>>(ei, deg);
    scan1_kernel<<<NB, 256, 0, stream>>>(deg, offsets, partial);
    scan2_kernel<<<1, 256, 0, stream>>>(partial, NB);
    scan3_kernel<<<NB, 256, 0, stream>>>(offsets, pos, partial);
    scatter_kernel<<<(N_EDGES + N_NODES + 255) / 256, 256, 0, stream>>>(ei, pos, csr);

    // 3 GAT layers
    const __half* Ain = x16;
    for (int l = 0; l < 3; ++l) {
        int K = (l == 0) ? FIN : HID;
        gemm_f16_kernel<<<dim3(N_NODES / 64, NCOLS / 64), 256, 0, stream>>>(Ain, W16[l], xh, K);
        scores2_kernel<<<(N_NODES + 31) / 32, 256, 0, stream>>>(Ain, vtab[l], ssrc, sdst, K);
        aggregate_kernel<<<(N_NODES + 3) / 4, 256, 0, stream>>>(xh, ssrc, sdst, offsets, csr,
                                                                Bb[l], Gg[l], Be[l], h16);
        Ain = h16;
    }

    // global mean pool + MLP head
    hipMemsetAsync(pooled, 0, (size_t)NGROUPS * HID * 4, stream);
    hipMemsetAsync(counts, 0, (size_t)NGROUPS * 4, stream);
    pool_kernel<<<(N_NODES + 255) / 256, 128, 0, stream>>>(h16, batch, pooled, counts);
    head_kernel<<<NGROUPS, 128, 0, stream>>>(pooled, counts, fc1_w, fc1_b, fc2_w, fc2_b,
                                             (float*)d_out);
}